// Round 16
// baseline (712.217 us; speedup 1.0000x reference)
//
#include <hip/hip_runtime.h>

// ---------------------------------------------------------------------------
// AdaLanczosNet forward, faithful f32 re-implementation of the JAX reference.
// B=16, N=256, NUM_ATOM=64, K=20, HIDDEN=(128,128), SCALES=10.
// Round 16: more dispatch merging (19 -> 15). sigred folded into arow (wave-0
// replication, bit-identical). spect folded into lanczos tail (wave-0 does all
// reductions with the original single-wave shfl code -> bit-identical gating;
// elementwise arrays spread over 512 threads). eig1 folded into layer-1 D1 as
// a 64-thread variant (acc[16] registers, same per-output order). ddE+longmsg
// fused into dlm (per-output ascending-l/k orders preserved).
// ---------------------------------------------------------------------------

constexpr int nB = 16;
constexpr int nN = 256;
constexpr int nK = 20;
constexpr int QS = nN + 1;  // padded Qb row stride (bank-conflict-free)
constexpr float EPSF = 1.1920928955078125e-07f;  // np.finfo(float32).eps
constexpr float LBF  = 1e-4f;                    // lanczos breakdown tol

#define DEV static __device__ __forceinline__

// ---------------- Threefry-2x32 (20 rounds) --------------------------------
DEV void tf2x32(unsigned k0, unsigned k1, unsigned x0, unsigned x1,
                unsigned &o0, unsigned &o1) {
  unsigned ks2 = k0 ^ k1 ^ 0x1BD11BDAu;
#define RND(r) { x0 += x1; x1 = (x1 << r) | (x1 >> (32 - r)); x1 ^= x0; }
  x0 += k0;  x1 += k1;
  RND(13) RND(15) RND(26) RND(6)
  x0 += k1;  x1 += ks2 + 1u;
  RND(17) RND(29) RND(16) RND(24)
  x0 += ks2; x1 += k0 + 2u;
  RND(13) RND(15) RND(26) RND(6)
  x0 += k0;  x1 += k1 + 3u;
  RND(17) RND(29) RND(16) RND(24)
  x0 += k1;  x1 += ks2 + 4u;
  RND(13) RND(15) RND(26) RND(6)
  x0 += ks2; x1 += k0 + 5u;
#undef RND
  o0 = x0; o1 = x1;
}

// XLA ErfInv (f32, Giles polynomial, w = -log1p(-x^2))
DEV float erfinv_f32(float x) {
  float w = -log1pf(-x * x);
  float p;
  if (w < 5.0f) {
    w -= 2.5f;
    p = 2.81022636e-08f;
    p = fmaf(p, w, 3.43273939e-07f);
    p = fmaf(p, w, -3.5233877e-06f);
    p = fmaf(p, w, -4.39150654e-06f);
    p = fmaf(p, w, 0.00021858087f);
    p = fmaf(p, w, -0.00125372503f);
    p = fmaf(p, w, -0.00417768164f);
    p = fmaf(p, w, 0.246640727f);
    p = fmaf(p, w, 1.50140941f);
  } else {
    w = sqrtf(w) - 3.0f;
    p = -0.000200214257f;
    p = fmaf(p, w, 0.000100950558f);
    p = fmaf(p, w, 0.00134934322f);
    p = fmaf(p, w, -0.00367342844f);
    p = fmaf(p, w, 0.00573950773f);
    p = fmaf(p, w, -0.0076224613f);
    p = fmaf(p, w, 0.00943887047f);
    p = fmaf(p, w, 1.00167406f);
    p = fmaf(p, w, 2.83297682f);
  }
  return p * x;
}

DEV float jax_normal(unsigned k0, unsigned k1, unsigned idx) {
  unsigned o0, o1;
  tf2x32(k0, k1, 0u /*hi*/, idx /*lo*/, o0, o1);
  unsigned bits = o0 ^ o1;
  float u = __uint_as_float((bits >> 9) | 0x3f800000u) - 1.0f;  // [0,1)
  const float lo = -0.99999994f;
  float v = fmaxf(lo, u * 2.0f + lo);
  return 1.41421356237309515f * erfinv_f32(v);
}

// ---------------- reductions ----------------------------------------------
DEV double waveRedD(double v) {
#pragma unroll
  for (int m = 32; m > 0; m >>= 1) v += __shfl_xor(v, m, 64);
  return v;
}
DEV float waveRedF(float v) {
#pragma unroll
  for (int m = 32; m > 0; m >>= 1) v += __shfl_xor(v, m, 64);
  return v;
}
DEV double blockSumD(double v, double *s4) {
  v = waveRedD(v);
  int w = threadIdx.x >> 6;
  __syncthreads();
  if ((threadIdx.x & 63) == 0) s4[w] = v;
  __syncthreads();
  return s4[0] + s4[1] + s4[2] + s4[3];
}
DEV double sum8(const double *r) {
  return ((r[0] + r[1]) + (r[2] + r[3])) + ((r[4] + r[5]) + (r[6] + r[7]));
}

// ---------------- stage 1: embedding table + one-hot state ----------------
__global__ __launch_bounds__(256) void feat_table_kernel(
    const float *__restrict__ w1, const float *__restrict__ b1,
    const float *__restrict__ w2, const float *__restrict__ b2,
    float *__restrict__ table) {
  int a = blockIdx.x, t = threadIdx.x;
  __shared__ float hh[1024];
  __shared__ float part[256];
  for (int k = t; k < 1024; k += 256)
    hh[k] = fmaxf(w1[(size_t)a * 1024 + k] + b1[k], 0.f);
  __syncthreads();
  int d = t & 63, slice = t >> 6;
  float acc = 0.f;
  for (int k = slice * 256; k < slice * 256 + 256; k++)
    acc += hh[k] * w2[(size_t)k * 64 + d];
  part[t] = acc;
  __syncthreads();
  if (t < 64)
    table[(size_t)a * 64 + t] =
        part[t] + part[64 + t] + part[128 + t] + part[192 + t] + b2[t];
}

// fused: feat gather + one-hot state + featT transpose (per 64-node tile)
__global__ __launch_bounds__(256) void feat_state_tr_kernel(
    const int *__restrict__ nf, const float *__restrict__ table,
    float *__restrict__ feat, float *__restrict__ featT,
    float *__restrict__ state0) {
  int g = blockIdx.x;             // nB*4
  int bb = g >> 2, n0 = (g & 3) * 64;
  int t = threadIdx.x;
  int c = t & 63, r4 = t >> 6;
  __shared__ float tl[64][65];
  __shared__ int av[64];
  if (t < 64) av[t] = nf[bb * nN + n0 + t];
  __syncthreads();
  for (int r = r4; r < 64; r += 4) {
    int a = av[r];
    float v = table[(size_t)a * 64 + c];
    tl[r][c] = v;
    feat[((size_t)(bb * nN + n0 + r)) * 64 + c] = v;
    state0[((size_t)(bb * nN + n0 + r)) * 64 + c] = (c == a) ? 1.f : 0.f;
  }
  __syncthreads();
  for (int r = r4; r < 64; r += 4)
    featT[(size_t)bb * 16384 + (size_t)r * nN + n0 + c] = tl[c][r];
}

// ---------------- stage 2: graph laplacian --------------------------------
__global__ __launch_bounds__(256) void dist2_kernel(
    const float *__restrict__ feat, const float *__restrict__ featT,
    float *__restrict__ G, double *__restrict__ part) {
  int g = blockIdx.x;             // nB*64
  int bb = g >> 6, i0 = (g & 63) * 4;
  int t = threadIdx.x;
  __shared__ float fi[4][64];
  __shared__ double s4[4];
  {
    int r = t >> 6, d = t & 63;
    fi[r][d] = feat[((size_t)(bb * nN + i0 + r)) * 64 + d];
  }
  __syncthreads();
  const float *ft = featT + (size_t)bb * 16384 + t;
  float a0 = 0.f, a1 = 0.f, a2 = 0.f, a3 = 0.f;
#pragma unroll 8
  for (int d = 0; d < 64; d++) {
    float x = ft[(size_t)d * nN];
    float d0 = fi[0][d] - x; a0 += d0 * d0;
    float d1 = fi[1][d] - x; a1 += d1 * d1;
    float d2 = fi[2][d] - x; a2 += d2 * d2;
    float d3 = fi[3][d] - x; a3 += d3 * d3;
  }
  size_t base = ((size_t)bb * nN + i0) * nN + t;
  G[base]           = a0;
  G[base + nN]      = a1;
  G[base + 2 * nN]  = a2;
  G[base + 3 * nN]  = a3;
  double tot = blockSumD((double)a0 + (double)a1 + (double)a2 + (double)a3, s4);
  if (t == 0) part[g] = tot;
}

// arow with sigred folded in (wave 0 replays sigred's exact 64-lane reduce)
__global__ __launch_bounds__(256) void arow_kernel(
    const float *__restrict__ Lfull, const double *__restrict__ part,
    float *__restrict__ G, float *__restrict__ Dv) {
  int g = blockIdx.x;
  int i = g % nN, bb = g / nN;
  int t = threadIdx.x;
  __shared__ double s4[4];
  __shared__ float ssig;
  if (t < 64) {
    double v = part[(size_t)bb * 64 + t];
    v = waveRedD(v);
    if (t == 0) ssig = (float)(v / 65536.0);
  }
  __syncthreads();
  float sig = ssig;
  size_t idx2 = ((size_t)bb * nN + i) * nN + t;
  float a = expf(-G[idx2] / sig) * Lfull[idx2 * 4];  // adj mask = L[...,0]
  G[idx2] = a;
  double rs = blockSumD((double)a, s4);
  if (t == 0) {
    float r = (float)rs;
    float pad = (r == 0.f) ? 1.f : 0.f;
    Dv[(size_t)bb * nN + i] = 1.f / sqrtf(r + pad);
  }
}

// scale G in place AND write GT = Lk^T (tiled transpose)
__global__ __launch_bounds__(256) void lkscale_tr_kernel(
    float *__restrict__ G, const float *__restrict__ Dv,
    float *__restrict__ GT) {
  int g = blockIdx.x;                 // nB*16
  int bb = g >> 4, tile = g & 15;
  int ti = (tile >> 2) * 64, tj = (tile & 3) * 64;
  int t = threadIdx.x;
  int lj = t & 63, li0 = t >> 6;
  __shared__ float tl[64][65];
  for (int r = li0; r < 64; r += 4) {
    int i = ti + r;
    size_t idx = ((size_t)bb * nN + i) * nN + tj + lj;
    float v = Dv[(size_t)bb * nN + i] * G[idx] * Dv[(size_t)bb * nN + tj + lj];
    G[idx] = v;
    tl[r][lj] = v;
  }
  __syncthreads();
  for (int r = li0; r < 64; r += 4) {
    int j = tj + r;
    GT[((size_t)bb * nN + j) * nN + ti + lj] = tl[lj][r];
  }
}

// ---------------- stage 3: Lanczos + spect tail (512 threads) --------------
__global__ __launch_bounds__(512)
void lanczos_kernel(const float *__restrict__ GT, float *__restrict__ Qout,
                    float *__restrict__ Tpow2) {
  __shared__ float Qb[nK * QS];          // padded stride 257
  __shared__ float qc[nN], qp[nN], zz[nN];
  __shared__ double zp[2][nN];
  __shared__ float qn2[nK], sAl[nK], sBe[nK], sVa[nK], coef[nK];
  __shared__ double redA[8], redB[8];
  // spect-tail arrays (used after main loop)
  __shared__ float sT[400], sTT[400], sTTn[400], sTb[nK], sTbn[nK];
  __shared__ float sKeep;
  int bb = blockIdx.x, u = threadIdx.x;
  int t = u & 255, h = u >> 8;
  int wv = u >> 6, lane = u & 63;
  int gid = u >> 4, gl = u & 15;

  const float *Gcol = GT + (size_t)bb * (nN * nN) + (size_t)(h * 128) * nN + t;

  unsigned k0, k1;
  tf2x32(0u, 42u, 0u, 0u, k0, k1);
  float val = 0.f;
  if (h == 0) val = jax_normal(k0, k1, (unsigned)(bb * nN + t));
  {
    double v = waveRedD((double)val * (double)val);
    __syncthreads();
    if (lane == 0) redA[wv] = v;
    __syncthreads();
    double n2 = sum8(redA);
    if (h == 0) {
      qc[t] = val / sqrtf((float)n2);
      qp[t] = 0.f;
    }
  }
  __syncthreads();

  float beta_prev = 0.f, validf = 1.f;

  for (int i = 0; i < nK; i++) {
    double a0 = 0, a1 = 0, a2 = 0, a3 = 0, a4 = 0, a5 = 0, a6 = 0, a7 = 0;
    {
      const float *qv = qc + h * 128;
#pragma unroll
      for (int jj = 0; jj < 128; jj += 8) {
        a0 += (double)Gcol[(size_t)(jj + 0) * nN] * (double)qv[jj + 0];
        a1 += (double)Gcol[(size_t)(jj + 1) * nN] * (double)qv[jj + 1];
        a2 += (double)Gcol[(size_t)(jj + 2) * nN] * (double)qv[jj + 2];
        a3 += (double)Gcol[(size_t)(jj + 3) * nN] * (double)qv[jj + 3];
        a4 += (double)Gcol[(size_t)(jj + 4) * nN] * (double)qv[jj + 4];
        a5 += (double)Gcol[(size_t)(jj + 5) * nN] * (double)qv[jj + 5];
        a6 += (double)Gcol[(size_t)(jj + 6) * nN] * (double)qv[jj + 6];
        a7 += (double)Gcol[(size_t)(jj + 7) * nN] * (double)qv[jj + 7];
      }
    }
    double part = ((a0 + a1) + (a2 + a3)) + ((a4 + a5) + (a6 + a7));
    zp[h][t] = part;
    double apart = (double)qc[t] * part;
    double qpart = (h == 0) ? (double)qc[t] * (double)qc[t] : 0.0;
    apart = waveRedD(apart);
    qpart = waveRedD(qpart);
    if (lane == 0) { redA[wv] = apart; redB[wv] = qpart; }
    __syncthreads();                                   // B1
    float alpha = (float)sum8(redA);
    if (h == 0) {
      float zi = (float)(zp[0][t] + zp[1][t]);
      zi = zi - alpha * qc[t] - beta_prev * qp[t];
      zz[t] = zi;
    } else {
      Qb[i * QS + t] = qc[t];
      if (t == 0) qn2[i] = (float)sum8(redB);
    }
    __syncthreads();                                   // B2
    if (gid < i) {
      double p = 0.0;
#pragma unroll
      for (int j = 0; j < 16; j++) {
        int n0 = gl + 16 * j;
        p += (double)Qb[gid * QS + n0] * (double)zz[n0];
      }
#pragma unroll
      for (int m = 1; m <= 8; m <<= 1) p += __shfl_xor(p, m, 64);
      if (gl == 0)
        coef[gid] = (float)(p / ((double)qn2[gid] + (double)EPSF));
    }
    __syncthreads();                                   // B3
    if (h == 0) {
      double sub = 0.0;
      for (int k = 0; k < i; k++)
        sub += (double)Qb[k * QS + t] * (double)coef[k];
      zz[t] = (float)((double)zz[t] - sub);
    }
    __syncthreads();                                   // B4
    if (gid < i) {
      double p = 0.0;
#pragma unroll
      for (int j = 0; j < 16; j++) {
        int n0 = gl + 16 * j;
        p += (double)Qb[gid * QS + n0] * (double)zz[n0];
      }
#pragma unroll
      for (int m = 1; m <= 8; m <<= 1) p += __shfl_xor(p, m, 64);
      if (gl == 0)
        coef[gid] = (float)(p / ((double)qn2[gid] + (double)EPSF));
    }
    __syncthreads();                                   // B5
    double bpart = 0.0;
    if (h == 0) {
      double sub = 0.0;
      for (int k = 0; k < i; k++)
        sub += (double)Qb[k * QS + t] * (double)coef[k];
      float znew = (float)((double)zz[t] - sub);
      zz[t] = znew;
      bpart = (double)znew * (double)znew;
    }
    bpart = waveRedD(bpart);
    if (lane == 0) redA[wv] = bpart;
    __syncthreads();                                   // B6
    float beta = sqrtf((float)sum8(redA));
    validf *= (beta >= LBF) ? 1.f : 0.f;
    if (u == 0) {
      sAl[i] = alpha;
      sBe[i] = beta;
      sVa[i] = validf;
    }
    if (h == 0) {
      float qnext = zz[t] * validf / (beta + EPSF);
      qp[t] = qc[t];
      qc[t] = qnext;
    }
    __syncthreads();                                   // B7
    beta_prev = beta;
  }

  // idx mask, Q output
  float idxf = 0.f;
  for (int k = 0; k < nK; k++) idxf += sVa[k];
  int idx = (int)idxf;
  if (h == 0) {
    float rowok = ((t < idx) || (idx >= nN)) ? 1.f : 0.f;
    for (int k = 0; k < nK; k++)
      Qout[((size_t)bb * nN + t) * nK + k] = Qb[k * QS + t] * sVa[k] * rowok;
  }
  // build T in LDS (same formula as the old Tout write)
  for (int e = u; e < nK * nK; e += 512) {
    int i = e / nK, j = e % nK;
    float v = 0.f;
    if (i == j) v = sAl[i] * sVa[i];
    else if (j == i + 1) v = sBe[i] * sVa[i];
    else if (i == j + 1) v = sBe[j] * sVa[j];
    sT[e] = v;
  }
  __syncthreads();

  // ---- spect tail: both layers (tt=0,1). Wave 0 does ALL reductions with
  // the original single-wave shfl code (bit-identical); elementwise arrays
  // spread over all 512 threads (per-element math unchanged).
  for (int tt = 0; tt < 2; tt++) {
    for (int e = u; e < nK * nK; e += 512) sTT[e] = sT[e];
    if (u < 64) {
      unsigned kk0, kk1;
      tf2x32(0u, 42u, 0u, (unsigned)(tt + 1), kk0, kk1);
      float tb = (u < nK) ? jax_normal(kk0, kk1, (unsigned)(bb * nK + u)) : 0.f;
      float pv = (u < nK) ? tb * tb : 0.f;
      float nb = sqrtf(waveRedF(pv));
      if (u < nK) sTb[u] = tb / nb;
    }
    __syncthreads();
    for (int ii = 0; ii < 8; ii++) {
      if (ii == 3 || ii == 5 || ii == 7) {
        int s = (ii - 3) / 2;
        int sf = tt * 3 + s;
        for (int e = u; e < nK * nK; e += 512)
          Tpow2[((size_t)sf * nB + bb) * nK * nK + e] = sTT[e];
      }
      __syncthreads();
      for (int e = u; e < nK * nK; e += 512) {
        int i = e / nK, j = e % nK;
        float a = 0.f;
        for (int l = 0; l < nK; l++) a += sTT[i * nK + l] * sT[l * nK + j];
        sTTn[e] = a;
      }
      if (u < nK) {
        float a = 0.f;
        for (int l = 0; l < nK; l++) a += sT[u * nK + l] * sTb[l];
        sTbn[u] = a;
      }
      __syncthreads();
      if (u < 64) {
        float pn = (u < nK) ? sTbn[u] * sTb[u] : 0.f;
        float pd = (u < nK) ? sTb[u] * sTb[u] : 0.f;
        float num = waveRedF(pn);
        float den = waveRedF(pd);
        float lmax = num / (den + EPSF);
        if (u == 0) sKeep = (fabsf(lmax) <= 1.0f) ? 1.f : 0.f;
      }
      __syncthreads();
      float keep = sKeep;
      for (int e = u; e < nK * nK; e += 512) sTT[e] = sTTn[e] * keep;
      if (u < 64) {
        float p2 = (u < nK) ? sTbn[u] * sTbn[u] : 0.f;
        float nn = sqrtf(waveRedF(p2));
        if (u < nK) sTb[u] = sTbn[u] / (nn + EPSF);
      }
      __syncthreads();
    }
    __syncthreads();
  }
}

// ---------------- msg bodies as device fns ---------------------------------
DEV void qtstate_body(const float *__restrict__ Q, const float *__restrict__ state,
                      float *__restrict__ E, int g, int t, int Din, char *smem) {
  int k = g % nK, bb = g / nK;
  float *qcol = (float *)smem;
  for (int n = t; n < nN; n += Din)
    qcol[n] = Q[((size_t)bb * nN + n) * nK + k];
  __syncthreads();
  const float *st = state + (size_t)bb * nN * Din;
  float acc = 0.f;
  for (int n = 0; n < nN; n++) acc += qcol[n] * st[(size_t)n * Din + t];
  E[((size_t)bb * nK + k) * Din + t] = acc;
}

DEV void lk_body(const float *__restrict__ Lk, const float *__restrict__ in,
                 int inStride, float *__restrict__ out, int outStride,
                 int g, int t, int Din, char *smem) {
  int bb = g >> 5, r0 = (g & 31) * 8;
  float (*rows)[nN] = (float (*)[nN])smem;
  for (int e = t; e < 8 * nN; e += Din) {
    int r = e >> 8, j = e & 255;
    rows[r][j] = Lk[((size_t)bb * nN + r0 + r) * nN + j];
  }
  __syncthreads();
  float acc[8] = {0.f, 0.f, 0.f, 0.f, 0.f, 0.f, 0.f, 0.f};
  const float *ip = in + (size_t)bb * nN * inStride + t;
  for (int j = 0; j < nN; j++) {
    float x = ip[(size_t)j * inStride];
#pragma unroll
    for (int r = 0; r < 8; r++) acc[r] += rows[r][j] * x;
  }
#pragma unroll
  for (int r = 0; r < 8; r++)
    out[((size_t)bb * nN + r0 + r) * outStride + t] = acc[r];
}

DEV void edgemsg_body(const float *__restrict__ Lfull,
                      const float *__restrict__ state, float *__restrict__ msg,
                      int C, int g, int t, int Din, char *smem) {
  int bb = g >> 6, r0 = (g & 63) * 4;
  float4 (*rows4)[nN] = (float4 (*)[nN])smem;
  const float4 *L4 = (const float4 *)Lfull;
  for (int e = t; e < 4 * nN; e += Din) {
    int r = e >> 8, j = e & 255;
    rows4[r][j] = L4[((size_t)bb * nN + r0 + r) * nN + j];
  }
  __syncthreads();
  float acc[4][4];
#pragma unroll
  for (int r = 0; r < 4; r++)
#pragma unroll
    for (int e = 0; e < 4; e++) acc[r][e] = 0.f;
  const float *st = state + (size_t)bb * nN * Din + t;
  for (int j = 0; j < nN; j++) {
    float x = st[(size_t)j * Din];
#pragma unroll
    for (int r = 0; r < 4; r++) {
      float4 lv = rows4[r][j];
      acc[r][0] += lv.x * x;
      acc[r][1] += lv.y * x;
      acc[r][2] += lv.z * x;
      acc[r][3] += lv.w * x;
    }
  }
#pragma unroll
  for (int r = 0; r < 4; r++)
#pragma unroll
    for (int e = 0; e < 4; e++)
      msg[((size_t)bb * nN + r0 + r) * C + (6 + e) * Din + t] = acc[r][e];
}

// eig1 at 64 threads: acc[16] registers, per-output order identical (bias +
// ascending k). Thread t handles output column o = t + oc*64 for all 16 bb.
DEV void eig1_body64(const float *__restrict__ Tpow2,
                     const float *__restrict__ w1p,
                     const float *__restrict__ b1p, float *__restrict__ h2,
                     int g, int t, char *smem) {
  int oc = g & 15, sf = g >> 4;
  int sw = sf % 3;
  int o = t + oc * 64;
  float *tp = (float *)smem;                 // nB*400 = 25.6 KiB
  for (int e = t; e < nB * 400; e += 64)
    tp[e] = Tpow2[(size_t)sf * nB * 400 + e];
  __syncthreads();
  float bias = b1p[(size_t)sw * 1024 + o];
  float acc[16];
#pragma unroll
  for (int b2 = 0; b2 < 16; b2++) acc[b2] = bias;
  const float *W = w1p + (size_t)sw * 400 * 1024 + o;
  for (int k = 0; k < 400; k++) {
    float w = W[(size_t)k * 1024];
#pragma unroll
    for (int b2 = 0; b2 < 16; b2++) acc[b2] += tp[b2 * 400 + k] * w;
  }
#pragma unroll
  for (int b2 = 0; b2 < 16; b2++)
    h2[((size_t)sf * nB + b2) * 1024 + o] = fmaxf(acc[b2], 0.f);
}

// eig2 body (256 threads)
DEV void eig2_body(const float *__restrict__ h2, const float *__restrict__ w2p,
                   const float *__restrict__ b2p, float *__restrict__ raw2,
                   int g, int t, char *smem) {
  int kc = g % 25, sf = g / 25;
  int sw = sf % 3;
  int kl = (t & 15) + kc * 16, bb = t >> 4;
  float *hh = (float *)smem;                 // nB*1025 = 65.6 KiB
  for (int e = t; e < nB * 1024; e += 256)
    hh[(e >> 10) * 1025 + (e & 1023)] = h2[(size_t)sf * nB * 1024 + e];
  __syncthreads();
  float acc = b2p[(size_t)sw * 400 + kl];
  const float *W = w2p + (size_t)sw * 1024 * 400 + kl;
  const float *hv = hh + bb * 1025;
  for (int o = 0; o < 1024; o++) acc += hv[o] * W[(size_t)o * 400];
  raw2[((size_t)sf * nB + bb) * 400 + kl] = acc;
}

// fused ddE+longmsg: per block = (bb, 16-row tile). F values computed with
// ddE's exact ascending-l order; msg outputs with longmsg's ascending-k.
DEV void dlm_body(const float *__restrict__ raw, const float *__restrict__ E,
                  const float *__restrict__ Q, float *__restrict__ msg,
                  int C, int g, int t, int Din, char *smem) {
  int bb = g >> 4, i0 = (g & 15) * 16;
  float *Es = (float *)smem;                 // nK*Din
  float *Fs = Es + nK * Din;                 // 3*nK*Din
  float *Qs = Fs + 3 * nK * Din;             // 16*nK
  for (int l = 0; l < nK; l++)
    Es[l * Din + t] = E[((size_t)bb * nK + l) * Din + t];
  for (int e = t; e < 16 * nK; e += Din)
    Qs[e] = Q[((size_t)bb * nN + i0 + e / nK) * nK + (e % nK)];
  __syncthreads();
  // F[s][k][.] = sum_l raw_sym * E  (ascending l; reads own-thread Es only)
  for (int sk = 0; sk < 3 * nK; sk++) {
    int s = sk / nK, k = sk % nK;
    const float *rp = raw + ((size_t)s * nB + bb) * 400;
    float acc = 0.f;
    for (int l = 0; l < nK; l++) {
      int mi = k < l ? k : l, ma = k < l ? l : k;
      acc += rp[mi * nK + ma] * Es[l * Din + t];
    }
    Fs[sk * Din + t] = acc;
  }
  // msg parts 3..5 (reads own-thread Fs; Qs via broadcast)
  for (int r = 0; r < 16; r++) {
    const float *qr = Qs + r * nK;
    for (int s = 0; s < 3; s++) {
      float acc = 0.f;
      for (int k = 0; k < nK; k++)
        acc += qr[k] * Fs[(s * nK + k) * Din + t];
      msg[((size_t)bb * nN + i0 + r) * C + (3 + s) * Din + t] = acc;
    }
  }
}

// ---------------- merged dispatches ----------------------------------------
// L1-D1 (64 thr): qtstate(320) || lk1(512) || edgemsg(1024) || eig1-64(96)
__global__ __launch_bounds__(64) void l1d1_kernel(
    const float *__restrict__ Q, const float *__restrict__ state,
    float *__restrict__ E, const float *__restrict__ Lk,
    float *__restrict__ msg, const float *__restrict__ Lfull,
    const float *__restrict__ Tpow2, const float *__restrict__ w1p,
    const float *__restrict__ b1p, float *__restrict__ h2, int C) {
  __shared__ __align__(16) char smem[26240];  // max(eig1 25.6K, edge 16K)
  int t = threadIdx.x;
  int gb = blockIdx.x;
  if (gb < 320) {
    qtstate_body(Q, state, E, gb, t, 64, smem);
  } else if (gb < 320 + 512) {
    lk_body(Lk, state, 64, msg + 0 * 64, C, gb - 320, t, 64, smem);
  } else if (gb < 320 + 512 + 1024) {
    edgemsg_body(Lfull, state, msg, C, gb - 832, t, 64, smem);
  } else {
    eig1_body64(Tpow2, w1p, b1p, h2, gb - 1856, t, smem);
  }
}

// L1-D2 (256 thr): eig2(150) || lk2(512, first-64-thread compute)
__global__ __launch_bounds__(256) void l1d2_kernel(
    const float *__restrict__ h2, const float *__restrict__ w2p,
    const float *__restrict__ b2p, float *__restrict__ raw2,
    const float *__restrict__ Lk, float *__restrict__ msg, int C) {
  __shared__ __align__(16) char smem[65600];  // max(eig2 65.6K, lk 8K)
  int t = threadIdx.x;
  int gb = blockIdx.x;
  if (gb < 150) {
    eig2_body(h2, w2p, b2p, raw2, gb, t, smem);
  } else {
    int g = gb - 150;
    int bb = g >> 5, r0 = (g & 31) * 8;
    float (*rows)[nN] = (float (*)[nN])smem;
    for (int e = t; e < 8 * nN; e += 256) {
      int r = e >> 8, j = e & 255;
      rows[r][j] = Lk[((size_t)bb * nN + r0 + r) * nN + j];
    }
    __syncthreads();
    if (t < 64) {
      float acc[8] = {0.f, 0.f, 0.f, 0.f, 0.f, 0.f, 0.f, 0.f};
      const float *ip = msg + (size_t)bb * nN * C + 0 * 64 + t;
      for (int j = 0; j < nN; j++) {
        float x = ip[(size_t)j * C];
#pragma unroll
        for (int r = 0; r < 8; r++) acc[r] += rows[r][j] * x;
      }
#pragma unroll
      for (int r = 0; r < 8; r++)
        msg[((size_t)bb * nN + r0 + r) * C + 1 * 64 + t] = acc[r];
    }
  }
}

// L1-D3 (64 thr): dlm(256) || lk3(512)
__global__ __launch_bounds__(64) void l1d3_kernel(
    const float *__restrict__ raw, const float *__restrict__ E,
    const float *__restrict__ Q, const float *__restrict__ Lk,
    float *__restrict__ msg, int C) {
  __shared__ __align__(16) char smem[22016];  // max(dlm 21.3K, lk 8K)
  int t = threadIdx.x;
  int gb = blockIdx.x;
  if (gb < 256) {
    dlm_body(raw, E, Q, msg, C, gb, t, 64, smem);
  } else {
    lk_body(Lk, msg + 1 * 64, C, msg + 2 * 64, C, gb - 256, t, 64, smem);
  }
}

// L2-D1 (128 thr): qtstate(320) || lk1(512) || edgemsg(1024)
__global__ __launch_bounds__(128) void l2d1_kernel(
    const float *__restrict__ Q, const float *__restrict__ state,
    float *__restrict__ E, const float *__restrict__ Lk,
    float *__restrict__ msg, const float *__restrict__ Lfull, int C) {
  __shared__ __align__(16) char smem[16384];
  int t = threadIdx.x;
  int gb = blockIdx.x;
  if (gb < 320) {
    qtstate_body(Q, state, E, gb, t, 128, smem);
  } else if (gb < 832) {
    lk_body(Lk, state, 128, msg + 0 * 128, C, gb - 320, t, 128, smem);
  } else {
    edgemsg_body(Lfull, state, msg, C, gb - 832, t, 128, smem);
  }
}

// L2-D2 (128 thr): dlm(256) || lk2(512)
__global__ __launch_bounds__(128) void l2d2_kernel(
    const float *__restrict__ raw, const float *__restrict__ E,
    const float *__restrict__ Q, const float *__restrict__ Lk,
    float *__restrict__ msg, int C) {
  __shared__ __align__(16) char smem[43328];  // dlm@128: (20+60)*128*4+1280
  int t = threadIdx.x;
  int gb = blockIdx.x;
  if (gb < 256) {
    dlm_body(raw, E, Q, msg, C, gb, t, 128, smem);
  } else {
    lk_body(Lk, msg + 0 * 128, C, msg + 1 * 128, C, gb - 256, t, 128, smem);
  }
}

// L2-D3 (128 thr): lk3 alone
__global__ __launch_bounds__(128) void l2d3_kernel(
    const float *__restrict__ Lk, float *__restrict__ msg, int C) {
  __shared__ __align__(16) char smem[8192];
  lk_body(Lk, msg + 1 * 128, C, msg + 2 * 128, C, blockIdx.x, threadIdx.x, 128,
          smem);
}

// state_next = relu(msg @ W + b); 16 rows/block, W k-chunk staged in LDS
__global__ __launch_bounds__(256) void filt_kernel(
    const float *__restrict__ msg, const float *__restrict__ W,
    const float *__restrict__ bias, float *__restrict__ out, int C) {
  int g = blockIdx.x;                 // (B*N)/16 = 256 blocks
  int base = g * 16;
  int t = threadIdx.x;
  int o = t & 127, ih = t >> 7;       // ih: 0/1 -> rows 0..7 / 8..15
  __shared__ float mt[16][64];        // 4 KiB
  __shared__ float wt[64][128];       // 32 KiB
  float acc[8];
  float bo = bias[o];
#pragma unroll
  for (int r = 0; r < 8; r++) acc[r] = bo;
  for (int c0 = 0; c0 < C; c0 += 64) {
    __syncthreads();
    for (int e = t; e < 16 * 64; e += 256) {
      int r = e >> 6, c = e & 63;
      mt[r][c] = msg[((size_t)(base + r)) * C + c0 + c];
    }
    for (int e = t; e < 64 * 128; e += 256)
      wt[e >> 7][e & 127] = W[(size_t)(c0 + (e >> 7)) * 128 + (e & 127)];
    __syncthreads();
    for (int c = 0; c < 64; c++) {
      float w = wt[c][o];
#pragma unroll
      for (int r = 0; r < 8; r++) acc[r] += mt[ih * 8 + r][c] * w;
    }
  }
#pragma unroll
  for (int r = 0; r < 8; r++)
    out[((size_t)(base + ih * 8 + r)) * 128 + o] = fmaxf(acc[r], 0.f);
}

// ---------------- stage 6: readout (LDS-staged coalesced reads) ------------
__global__ __launch_bounds__(256) void score_kernel(
    const float *__restrict__ state, const float *__restrict__ wo,
    const float *__restrict__ bo, const float *__restrict__ aw,
    const float *__restrict__ ab, float *__restrict__ out) {
  __shared__ float sl[64 * 129];      // 33 KiB, bank-safe stride
  __shared__ double s4[4];
  int bb = blockIdx.x, t = threadIdx.x;
  float bof = bo[0], abf = ab[0];
  double dsum = 0.0;
  for (int r0 = 0; r0 < nN; r0 += 64) {
    __syncthreads();
    for (int e = t; e < 64 * 128; e += 256) {
      int r = e >> 7, o = e & 127;
      sl[r * 129 + o] = state[((size_t)bb * nN + r0 + r) * 128 + o];
    }
    __syncthreads();
    if (t < 64) {
      const float *sr = sl + t * 129;
      float sy = bof, sa = abf;
      for (int o = 0; o < 128; o++) {
        float v = sr[o];
        sy += v * wo[o];
        sa += v * aw[o];
      }
      float att = 1.f / (1.f + expf(-sa));
      dsum += (double)(att * sy);
    }
  }
  double m = blockSumD(dsum, s4);
  if (t == 0) out[bb] = (float)(m / (double)nN);
}

// ---------------------------------------------------------------------------
extern "C" void kernel_launch(void *const *d_in, const int *in_sizes, int n_in,
                              void *d_out, int out_size, void *d_ws,
                              size_t ws_size, hipStream_t stream) {
  (void)in_sizes; (void)n_in; (void)out_size;
  const int   *node_feat = (const int *)d_in[0];
  const float *Lfull     = (const float *)d_in[1];
  const float *emb_w1    = (const float *)d_in[2];
  const float *emb_b1    = (const float *)d_in[3];
  const float *emb_w2    = (const float *)d_in[4];
  const float *emb_b2    = (const float *)d_in[5];
  const float *eig_w1    = (const float *)d_in[6];
  const float *eig_b1    = (const float *)d_in[7];
  const float *eig_w2    = (const float *)d_in[8];
  const float *eig_b2    = (const float *)d_in[9];
  const float *filt_w0   = (const float *)d_in[10];
  const float *filt_b0   = (const float *)d_in[11];
  const float *filt_w1   = (const float *)d_in[12];
  const float *filt_b1   = (const float *)d_in[13];
  const float *filt_wo   = (const float *)d_in[14];
  const float *filt_bo   = (const float *)d_in[15];
  const float *att_w     = (const float *)d_in[16];
  const float *att_b     = (const float *)d_in[17];

  // workspace layout (floats)
  float *ws   = (float *)d_ws;
  float *G    = ws;                    // B*N*N           = 1048576
  float *msg  = G + 1048576;           // B*N*1280        = 5242880
  float *st0  = msg + 5242880;         // B*N*64
  float *st1  = st0 + 262144;          // B*N*128
  float *st2  = st1 + 524288;          // B*N*128
  float *feat = st2 + 524288;          // B*N*64  (dead after dist2)
  float *table= feat + 262144;         // 64*64
  float *Q    = table + 4096;          // B*N*K
  float *T    = Q + 81920;             // (unused; layout kept)
  float *Tpow = T + 6400;              // (layout kept)
  float *DD   = Tpow + 19200;          // (layout kept)
  float *h    = DD + 19200;            // (layout kept)
  float *E    = h + 49152;             // B*K*128
  float *F    = E + 40960;             // 3*B*K*128 (unused; layout kept)
  float *Dv   = F + 122880;            // B*N
  double *part   = (double *)(Dv + 4096);   // B*N doubles (8-byte aligned)
  // aliases of dead regions:
  float *GT    = msg;                  // B*N*N (dead after lanczos)
  float *featT = msg + 1048576;        // B*64*256 (dead after dist2)
  float *Tpow2 = feat;                 // 2*3*B*400 = 38400
  float *raw2  = feat + 38400;         // 38400
  float *h2    = feat + 76800;         // 98304 (total 175104 < 262144)
  const size_t needBytes = (size_t)(8220432) * 4;
  if (ws_size < needBytes) return;

  // front-end
  feat_table_kernel<<<64, 256, 0, stream>>>(emb_w1, emb_b1, emb_w2, emb_b2, table);
  feat_state_tr_kernel<<<nB * 4, 256, 0, stream>>>(node_feat, table, feat,
                                                   featT, st0);
  dist2_kernel<<<nB * 64, 256, 0, stream>>>(feat, featT, G, part);
  arow_kernel<<<nB * nN, 256, 0, stream>>>(Lfull, part, G, Dv);
  lkscale_tr_kernel<<<nB * 16, 256, 0, stream>>>(G, Dv, GT);
  // lanczos (+ spect for both layers in its tail)
  lanczos_kernel<<<nB, 512, 0, stream>>>(GT, Q, Tpow2);

  // ---- layer 1 (Din = 64) ----
  {
    int C = 640;
    const float *rawT = raw2;  // tt=0 slice
    l1d1_kernel<<<320 + 512 + 1024 + 96, 64, 0, stream>>>(
        Q, st0, E, G, msg, Lfull, Tpow2, eig_w1, eig_b1, h2, C);
    l1d2_kernel<<<150 + 512, 256, 0, stream>>>(h2, eig_w2, eig_b2, raw2, G,
                                               msg, C);
    l1d3_kernel<<<256 + 512, 64, 0, stream>>>(rawT, E, Q, G, msg, C);
    filt_kernel<<<nB * nN / 16, 256, 0, stream>>>(msg, filt_w0, filt_b0, st1, C);
  }
  // ---- layer 2 (Din = 128) ----
  {
    int C = 1280;
    const float *rawT = raw2 + (size_t)3 * nB * 400;  // tt=1 slice
    l2d1_kernel<<<320 + 512 + 1024, 128, 0, stream>>>(Q, st1, E, G, msg,
                                                      Lfull, C);
    l2d2_kernel<<<256 + 512, 128, 0, stream>>>(rawT, E, Q, G, msg, C);
    l2d3_kernel<<<512, 128, 0, stream>>>(G, msg, C);
    filt_kernel<<<nB * nN / 16, 256, 0, stream>>>(msg, filt_w1, filt_b1, st2, C);
  }
  score_kernel<<<nB, 256, 0, stream>>>(st2, filt_wo, filt_bo, att_w, att_b,
                                       (float *)d_out);
}

// Round 17
// 630.828 us; speedup vs baseline: 1.1290x; 1.1290x over previous
//
#include <hip/hip_runtime.h>

// ---------------------------------------------------------------------------
// AdaLanczosNet forward, faithful f32 re-implementation of the JAX reference.
// B=16, N=256, NUM_ATOM=64, K=20, HIDDEN=(128,128), SCALES=10.
// Round 17: revert r16 (merges that changed body shapes regressed: lanczos
// absorbed spect at 16-block parallelism +11us; dlm/eig1-64 serialized work).
// = r15 champion (632us) + ONLY the sigred->arow fold (body shapes unchanged;
// wave-0 replays sigred's exact 64-lane butterfly -> bit-identical sigma2).
// ---------------------------------------------------------------------------

constexpr int nB = 16;
constexpr int nN = 256;
constexpr int nK = 20;
constexpr int QS = nN + 1;  // padded Qb row stride (bank-conflict-free)
constexpr float EPSF = 1.1920928955078125e-07f;  // np.finfo(float32).eps
constexpr float LBF  = 1e-4f;                    // lanczos breakdown tol

#define DEV static __device__ __forceinline__

// ---------------- Threefry-2x32 (20 rounds) --------------------------------
DEV void tf2x32(unsigned k0, unsigned k1, unsigned x0, unsigned x1,
                unsigned &o0, unsigned &o1) {
  unsigned ks2 = k0 ^ k1 ^ 0x1BD11BDAu;
#define RND(r) { x0 += x1; x1 = (x1 << r) | (x1 >> (32 - r)); x1 ^= x0; }
  x0 += k0;  x1 += k1;
  RND(13) RND(15) RND(26) RND(6)
  x0 += k1;  x1 += ks2 + 1u;
  RND(17) RND(29) RND(16) RND(24)
  x0 += ks2; x1 += k0 + 2u;
  RND(13) RND(15) RND(26) RND(6)
  x0 += k0;  x1 += k1 + 3u;
  RND(17) RND(29) RND(16) RND(24)
  x0 += k1;  x1 += ks2 + 4u;
  RND(13) RND(15) RND(26) RND(6)
  x0 += ks2; x1 += k0 + 5u;
#undef RND
  o0 = x0; o1 = x1;
}

// XLA ErfInv (f32, Giles polynomial, w = -log1p(-x^2))
DEV float erfinv_f32(float x) {
  float w = -log1pf(-x * x);
  float p;
  if (w < 5.0f) {
    w -= 2.5f;
    p = 2.81022636e-08f;
    p = fmaf(p, w, 3.43273939e-07f);
    p = fmaf(p, w, -3.5233877e-06f);
    p = fmaf(p, w, -4.39150654e-06f);
    p = fmaf(p, w, 0.00021858087f);
    p = fmaf(p, w, -0.00125372503f);
    p = fmaf(p, w, -0.00417768164f);
    p = fmaf(p, w, 0.246640727f);
    p = fmaf(p, w, 1.50140941f);
  } else {
    w = sqrtf(w) - 3.0f;
    p = -0.000200214257f;
    p = fmaf(p, w, 0.000100950558f);
    p = fmaf(p, w, 0.00134934322f);
    p = fmaf(p, w, -0.00367342844f);
    p = fmaf(p, w, 0.00573950773f);
    p = fmaf(p, w, -0.0076224613f);
    p = fmaf(p, w, 0.00943887047f);
    p = fmaf(p, w, 1.00167406f);
    p = fmaf(p, w, 2.83297682f);
  }
  return p * x;
}

DEV float jax_normal(unsigned k0, unsigned k1, unsigned idx) {
  unsigned o0, o1;
  tf2x32(k0, k1, 0u /*hi*/, idx /*lo*/, o0, o1);
  unsigned bits = o0 ^ o1;
  float u = __uint_as_float((bits >> 9) | 0x3f800000u) - 1.0f;  // [0,1)
  const float lo = -0.99999994f;
  float v = fmaxf(lo, u * 2.0f + lo);
  return 1.41421356237309515f * erfinv_f32(v);
}

// ---------------- reductions ----------------------------------------------
DEV double waveRedD(double v) {
#pragma unroll
  for (int m = 32; m > 0; m >>= 1) v += __shfl_xor(v, m, 64);
  return v;
}
DEV float waveRedF(float v) {
#pragma unroll
  for (int m = 32; m > 0; m >>= 1) v += __shfl_xor(v, m, 64);
  return v;
}
DEV double blockSumD(double v, double *s4) {
  v = waveRedD(v);
  int w = threadIdx.x >> 6;
  __syncthreads();
  if ((threadIdx.x & 63) == 0) s4[w] = v;
  __syncthreads();
  return s4[0] + s4[1] + s4[2] + s4[3];
}
DEV double sum8(const double *r) {
  return ((r[0] + r[1]) + (r[2] + r[3])) + ((r[4] + r[5]) + (r[6] + r[7]));
}

// ---------------- stage 1: embedding table + one-hot state ----------------
__global__ __launch_bounds__(256) void feat_table_kernel(
    const float *__restrict__ w1, const float *__restrict__ b1,
    const float *__restrict__ w2, const float *__restrict__ b2,
    float *__restrict__ table) {
  int a = blockIdx.x, t = threadIdx.x;
  __shared__ float hh[1024];
  __shared__ float part[256];
  for (int k = t; k < 1024; k += 256)
    hh[k] = fmaxf(w1[(size_t)a * 1024 + k] + b1[k], 0.f);
  __syncthreads();
  int d = t & 63, slice = t >> 6;
  float acc = 0.f;
  for (int k = slice * 256; k < slice * 256 + 256; k++)
    acc += hh[k] * w2[(size_t)k * 64 + d];
  part[t] = acc;
  __syncthreads();
  if (t < 64)
    table[(size_t)a * 64 + t] =
        part[t] + part[64 + t] + part[128 + t] + part[192 + t] + b2[t];
}

// fused: feat gather + one-hot state + featT transpose (per 64-node tile)
__global__ __launch_bounds__(256) void feat_state_tr_kernel(
    const int *__restrict__ nf, const float *__restrict__ table,
    float *__restrict__ feat, float *__restrict__ featT,
    float *__restrict__ state0) {
  int g = blockIdx.x;             // nB*4
  int bb = g >> 2, n0 = (g & 3) * 64;
  int t = threadIdx.x;
  int c = t & 63, r4 = t >> 6;
  __shared__ float tl[64][65];
  __shared__ int av[64];
  if (t < 64) av[t] = nf[bb * nN + n0 + t];
  __syncthreads();
  for (int r = r4; r < 64; r += 4) {
    int a = av[r];
    float v = table[(size_t)a * 64 + c];
    tl[r][c] = v;
    feat[((size_t)(bb * nN + n0 + r)) * 64 + c] = v;
    state0[((size_t)(bb * nN + n0 + r)) * 64 + c] = (c == a) ? 1.f : 0.f;
  }
  __syncthreads();
  for (int r = r4; r < 64; r += 4)
    featT[(size_t)bb * 16384 + (size_t)r * nN + n0 + c] = tl[c][r];
}

// ---------------- stage 2: graph laplacian --------------------------------
__global__ __launch_bounds__(256) void dist2_kernel(
    const float *__restrict__ feat, const float *__restrict__ featT,
    float *__restrict__ G, double *__restrict__ part) {
  int g = blockIdx.x;             // nB*64
  int bb = g >> 6, i0 = (g & 63) * 4;
  int t = threadIdx.x;
  __shared__ float fi[4][64];
  __shared__ double s4[4];
  {
    int r = t >> 6, d = t & 63;
    fi[r][d] = feat[((size_t)(bb * nN + i0 + r)) * 64 + d];
  }
  __syncthreads();
  const float *ft = featT + (size_t)bb * 16384 + t;
  float a0 = 0.f, a1 = 0.f, a2 = 0.f, a3 = 0.f;
#pragma unroll 8
  for (int d = 0; d < 64; d++) {
    float x = ft[(size_t)d * nN];
    float d0 = fi[0][d] - x; a0 += d0 * d0;
    float d1 = fi[1][d] - x; a1 += d1 * d1;
    float d2 = fi[2][d] - x; a2 += d2 * d2;
    float d3 = fi[3][d] - x; a3 += d3 * d3;
  }
  size_t base = ((size_t)bb * nN + i0) * nN + t;
  G[base]           = a0;
  G[base + nN]      = a1;
  G[base + 2 * nN]  = a2;
  G[base + 3 * nN]  = a3;
  double tot = blockSumD((double)a0 + (double)a1 + (double)a2 + (double)a3, s4);
  if (t == 0) part[g] = tot;
}

// arow with sigred folded in (wave 0 replays sigred's exact 64-lane reduce)
__global__ __launch_bounds__(256) void arow_kernel(
    const float *__restrict__ Lfull, const double *__restrict__ part,
    float *__restrict__ G, float *__restrict__ Dv) {
  int g = blockIdx.x;
  int i = g % nN, bb = g / nN;
  int t = threadIdx.x;
  __shared__ double s4[4];
  __shared__ float ssig;
  if (t < 64) {
    double v = part[(size_t)bb * 64 + t];
    v = waveRedD(v);
    if (t == 0) ssig = (float)(v / 65536.0);
  }
  __syncthreads();
  float sig = ssig;
  size_t idx2 = ((size_t)bb * nN + i) * nN + t;
  float a = expf(-G[idx2] / sig) * Lfull[idx2 * 4];  // adj mask = L[...,0]
  G[idx2] = a;
  double rs = blockSumD((double)a, s4);
  if (t == 0) {
    float r = (float)rs;
    float pad = (r == 0.f) ? 1.f : 0.f;
    Dv[(size_t)bb * nN + i] = 1.f / sqrtf(r + pad);
  }
}

// scale G in place AND write GT = Lk^T (tiled transpose)
__global__ __launch_bounds__(256) void lkscale_tr_kernel(
    float *__restrict__ G, const float *__restrict__ Dv,
    float *__restrict__ GT) {
  int g = blockIdx.x;                 // nB*16
  int bb = g >> 4, tile = g & 15;
  int ti = (tile >> 2) * 64, tj = (tile & 3) * 64;
  int t = threadIdx.x;
  int lj = t & 63, li0 = t >> 6;
  __shared__ float tl[64][65];
  for (int r = li0; r < 64; r += 4) {
    int i = ti + r;
    size_t idx = ((size_t)bb * nN + i) * nN + tj + lj;
    float v = Dv[(size_t)bb * nN + i] * G[idx] * Dv[(size_t)bb * nN + tj + lj];
    G[idx] = v;
    tl[r][lj] = v;
  }
  __syncthreads();
  for (int r = li0; r < 64; r += 4) {
    int j = tj + r;
    GT[((size_t)bb * nN + j) * nN + ti + lj] = tl[lj][r];
  }
}

// ---------------- stage 3: Lanczos (512 threads, streamed matvec) ---------
__global__ __launch_bounds__(512)
void lanczos_kernel(const float *__restrict__ GT, float *__restrict__ Qout,
                    float *__restrict__ Tout) {
  __shared__ float Qb[nK * QS];          // padded stride 257
  __shared__ float qc[nN], qp[nN], zz[nN];
  __shared__ double zp[2][nN];
  __shared__ float qn2[nK], sAl[nK], sBe[nK], sVa[nK], coef[nK];
  __shared__ double redA[8], redB[8];
  int bb = blockIdx.x, u = threadIdx.x;
  int t = u & 255, h = u >> 8;
  int wv = u >> 6, lane = u & 63;
  int gid = u >> 4, gl = u & 15;

  const float *Gcol = GT + (size_t)bb * (nN * nN) + (size_t)(h * 128) * nN + t;

  unsigned k0, k1;
  tf2x32(0u, 42u, 0u, 0u, k0, k1);
  float val = 0.f;
  if (h == 0) val = jax_normal(k0, k1, (unsigned)(bb * nN + t));
  {
    double v = waveRedD((double)val * (double)val);
    __syncthreads();
    if (lane == 0) redA[wv] = v;
    __syncthreads();
    double n2 = sum8(redA);
    if (h == 0) {
      qc[t] = val / sqrtf((float)n2);
      qp[t] = 0.f;
    }
  }
  __syncthreads();

  float beta_prev = 0.f, validf = 1.f;

  for (int i = 0; i < nK; i++) {
    double a0 = 0, a1 = 0, a2 = 0, a3 = 0, a4 = 0, a5 = 0, a6 = 0, a7 = 0;
    {
      const float *qv = qc + h * 128;
#pragma unroll
      for (int jj = 0; jj < 128; jj += 8) {
        a0 += (double)Gcol[(size_t)(jj + 0) * nN] * (double)qv[jj + 0];
        a1 += (double)Gcol[(size_t)(jj + 1) * nN] * (double)qv[jj + 1];
        a2 += (double)Gcol[(size_t)(jj + 2) * nN] * (double)qv[jj + 2];
        a3 += (double)Gcol[(size_t)(jj + 3) * nN] * (double)qv[jj + 3];
        a4 += (double)Gcol[(size_t)(jj + 4) * nN] * (double)qv[jj + 4];
        a5 += (double)Gcol[(size_t)(jj + 5) * nN] * (double)qv[jj + 5];
        a6 += (double)Gcol[(size_t)(jj + 6) * nN] * (double)qv[jj + 6];
        a7 += (double)Gcol[(size_t)(jj + 7) * nN] * (double)qv[jj + 7];
      }
    }
    double part = ((a0 + a1) + (a2 + a3)) + ((a4 + a5) + (a6 + a7));
    zp[h][t] = part;
    double apart = (double)qc[t] * part;
    double qpart = (h == 0) ? (double)qc[t] * (double)qc[t] : 0.0;
    apart = waveRedD(apart);
    qpart = waveRedD(qpart);
    if (lane == 0) { redA[wv] = apart; redB[wv] = qpart; }
    __syncthreads();                                   // B1
    float alpha = (float)sum8(redA);
    if (h == 0) {
      float zi = (float)(zp[0][t] + zp[1][t]);
      zi = zi - alpha * qc[t] - beta_prev * qp[t];
      zz[t] = zi;
    } else {
      Qb[i * QS + t] = qc[t];
      if (t == 0) qn2[i] = (float)sum8(redB);
    }
    __syncthreads();                                   // B2
    if (gid < i) {
      double p = 0.0;
#pragma unroll
      for (int j = 0; j < 16; j++) {
        int n0 = gl + 16 * j;
        p += (double)Qb[gid * QS + n0] * (double)zz[n0];
      }
#pragma unroll
      for (int m = 1; m <= 8; m <<= 1) p += __shfl_xor(p, m, 64);
      if (gl == 0)
        coef[gid] = (float)(p / ((double)qn2[gid] + (double)EPSF));
    }
    __syncthreads();                                   // B3
    if (h == 0) {
      double sub = 0.0;
      for (int k = 0; k < i; k++)
        sub += (double)Qb[k * QS + t] * (double)coef[k];
      zz[t] = (float)((double)zz[t] - sub);
    }
    __syncthreads();                                   // B4
    if (gid < i) {
      double p = 0.0;
#pragma unroll
      for (int j = 0; j < 16; j++) {
        int n0 = gl + 16 * j;
        p += (double)Qb[gid * QS + n0] * (double)zz[n0];
      }
#pragma unroll
      for (int m = 1; m <= 8; m <<= 1) p += __shfl_xor(p, m, 64);
      if (gl == 0)
        coef[gid] = (float)(p / ((double)qn2[gid] + (double)EPSF));
    }
    __syncthreads();                                   // B5
    double bpart = 0.0;
    if (h == 0) {
      double sub = 0.0;
      for (int k = 0; k < i; k++)
        sub += (double)Qb[k * QS + t] * (double)coef[k];
      float znew = (float)((double)zz[t] - sub);
      zz[t] = znew;
      bpart = (double)znew * (double)znew;
    }
    bpart = waveRedD(bpart);
    if (lane == 0) redA[wv] = bpart;
    __syncthreads();                                   // B6
    float beta = sqrtf((float)sum8(redA));
    validf *= (beta >= LBF) ? 1.f : 0.f;
    if (u == 0) {
      sAl[i] = alpha;
      sBe[i] = beta;
      sVa[i] = validf;
    }
    if (h == 0) {
      float qnext = zz[t] * validf / (beta + EPSF);
      qp[t] = qc[t];
      qc[t] = qnext;
    }
    __syncthreads();                                   // B7
    beta_prev = beta;
  }

  float idxf = 0.f;
  for (int k = 0; k < nK; k++) idxf += sVa[k];
  int idx = (int)idxf;
  if (h == 0) {
    float rowok = ((t < idx) || (idx >= nN)) ? 1.f : 0.f;
    for (int k = 0; k < nK; k++)
      Qout[((size_t)bb * nN + t) * nK + k] = Qb[k * QS + t] * sVa[k] * rowok;
  }
  for (int e = u; e < nK * nK; e += 512) {
    int i = e / nK, j = e % nK;
    float v = 0.f;
    if (i == j) v = sAl[i] * sVa[i];
    else if (j == i + 1) v = sBe[i] * sVa[i];
    else if (i == j + 1) v = sBe[j] * sVa[j];
    Tout[(size_t)bb * nK * nK + e] = v;
  }
}

// ---------------- spect_power body (device fn; 64 threads) -----------------
DEV void spect_body(const float *__restrict__ Tin, float *__restrict__ Tpow2,
                    int bb, int tt, int t, char *smem) {
  float *T_  = (float *)smem;                // 400
  float *TT  = T_ + nK * nK;                 // 400
  float *TTn = TT + nK * nK;                 // 400
  float *Tb  = TTn + nK * nK;                // 20
  float *Tbn = Tb + nK;                      // 20
  for (int e = t; e < nK * nK; e += 64) {
    float v = Tin[(size_t)bb * nK * nK + e];
    T_[e] = v;
    TT[e] = v;
  }
  unsigned k0, k1;
  tf2x32(0u, 42u, 0u, (unsigned)(tt + 1), k0, k1);
  if (t < nK) Tb[t] = jax_normal(k0, k1, (unsigned)(bb * nK + t));
  __syncthreads();
  float pv = (t < nK) ? Tb[t] * Tb[t] : 0.f;
  float nb = sqrtf(waveRedF(pv));
  if (t < nK) Tb[t] = Tb[t] / nb;
  __syncthreads();
  for (int ii = 0; ii < 8; ii++) {
    if (ii == 3 || ii == 5 || ii == 7) {
      int s = (ii - 3) / 2;
      int sf = tt * 3 + s;
      for (int e = t; e < nK * nK; e += 64)
        Tpow2[((size_t)sf * nB + bb) * nK * nK + e] = TT[e];
    }
    __syncthreads();
    for (int e = t; e < nK * nK; e += 64) {
      int i = e / nK, j = e % nK;
      float a = 0.f;
      for (int l = 0; l < nK; l++) a += TT[i * nK + l] * T_[l * nK + j];
      TTn[e] = a;
    }
    if (t < nK) {
      float a = 0.f;
      for (int l = 0; l < nK; l++) a += T_[t * nK + l] * Tb[l];
      Tbn[t] = a;
    }
    __syncthreads();
    float pn = (t < nK) ? Tbn[t] * Tb[t] : 0.f;
    float pd = (t < nK) ? Tb[t] * Tb[t] : 0.f;
    float num = waveRedF(pn);
    float den = waveRedF(pd);
    float lmax = num / (den + EPSF);
    float keep = (fabsf(lmax) <= 1.0f) ? 1.f : 0.f;
    __syncthreads();
    for (int e = t; e < nK * nK; e += 64) TT[e] = TTn[e] * keep;
    float p2 = (t < nK) ? Tbn[t] * Tbn[t] : 0.f;
    float nn = sqrtf(waveRedF(p2));
    if (t < nK) Tb[t] = Tbn[t] / (nn + EPSF);
    __syncthreads();
  }
}

// ---------------- eig1 body (device fn; 256 threads) -----------------------
DEV void eig1_body(const float *__restrict__ Tpow2, const float *__restrict__ w1p,
                   const float *__restrict__ b1p, float *__restrict__ h2,
                   int g, int t, char *smem) {
  int oc = g & 15, sf = g >> 4;
  int sw = sf % 3;
  int o = (t & 63) + oc * 64, bbg = t >> 6;
  float *tp = (float *)smem;                 // nB*400 = 25.6 KiB
  for (int e = t; e < nB * 400; e += 256)
    tp[e] = Tpow2[(size_t)sf * nB * 400 + e];
  __syncthreads();
  float bias = b1p[(size_t)sw * 1024 + o];
  float acc0 = bias, acc1 = bias, acc2 = bias, acc3 = bias;
  const float *W = w1p + (size_t)sw * 400 * 1024 + o;
  const float *t0 = tp + (bbg + 0) * 400;
  const float *t1 = tp + (bbg + 4) * 400;
  const float *t2 = tp + (bbg + 8) * 400;
  const float *t3 = tp + (bbg + 12) * 400;
  for (int k = 0; k < 400; k++) {
    float w = W[(size_t)k * 1024];
    acc0 += t0[k] * w;
    acc1 += t1[k] * w;
    acc2 += t2[k] * w;
    acc3 += t3[k] * w;
  }
  h2[((size_t)sf * nB + (bbg + 0))  * 1024 + o] = fmaxf(acc0, 0.f);
  h2[((size_t)sf * nB + (bbg + 4))  * 1024 + o] = fmaxf(acc1, 0.f);
  h2[((size_t)sf * nB + (bbg + 8))  * 1024 + o] = fmaxf(acc2, 0.f);
  h2[((size_t)sf * nB + (bbg + 12)) * 1024 + o] = fmaxf(acc3, 0.f);
}

// ---------------- eig2 body (device fn; 256 threads) -----------------------
DEV void eig2_body(const float *__restrict__ h2, const float *__restrict__ w2p,
                   const float *__restrict__ b2p, float *__restrict__ raw2,
                   int g, int t, char *smem) {
  int kc = g % 25, sf = g / 25;
  int sw = sf % 3;
  int kl = (t & 15) + kc * 16, bb = t >> 4;
  float *hh = (float *)smem;                 // nB*1025 = 65.6 KiB
  for (int e = t; e < nB * 1024; e += 256)
    hh[(e >> 10) * 1025 + (e & 1023)] = h2[(size_t)sf * nB * 1024 + e];
  __syncthreads();
  float acc = b2p[(size_t)sw * 400 + kl];
  const float *W = w2p + (size_t)sw * 1024 * 400 + kl;
  const float *hv = hh + bb * 1025;
  for (int o = 0; o < 1024; o++) acc += hv[o] * W[(size_t)o * 400];
  raw2[((size_t)sf * nB + bb) * 400 + kl] = acc;
}

// ---------------- r12 msg bodies as device fns -----------------------------
DEV void qtstate_body(const float *__restrict__ Q, const float *__restrict__ state,
                      float *__restrict__ E, int g, int t, int Din, char *smem) {
  int k = g % nK, bb = g / nK;
  float *qcol = (float *)smem;
  for (int n = t; n < nN; n += Din)
    qcol[n] = Q[((size_t)bb * nN + n) * nK + k];
  __syncthreads();
  const float *st = state + (size_t)bb * nN * Din;
  float acc = 0.f;
  for (int n = 0; n < nN; n++) acc += qcol[n] * st[(size_t)n * Din + t];
  E[((size_t)bb * nK + k) * Din + t] = acc;
}

DEV void lk_body(const float *__restrict__ Lk, const float *__restrict__ in,
                 int inStride, float *__restrict__ out, int outStride,
                 int g, int t, int Din, char *smem) {
  int bb = g >> 5, r0 = (g & 31) * 8;
  float (*rows)[nN] = (float (*)[nN])smem;
  for (int e = t; e < 8 * nN; e += Din) {
    int r = e >> 8, j = e & 255;
    rows[r][j] = Lk[((size_t)bb * nN + r0 + r) * nN + j];
  }
  __syncthreads();
  float acc[8] = {0.f, 0.f, 0.f, 0.f, 0.f, 0.f, 0.f, 0.f};
  const float *ip = in + (size_t)bb * nN * inStride + t;
  for (int j = 0; j < nN; j++) {
    float x = ip[(size_t)j * inStride];
#pragma unroll
    for (int r = 0; r < 8; r++) acc[r] += rows[r][j] * x;
  }
#pragma unroll
  for (int r = 0; r < 8; r++)
    out[((size_t)bb * nN + r0 + r) * outStride + t] = acc[r];
}

DEV void edgemsg_body(const float *__restrict__ Lfull,
                      const float *__restrict__ state, float *__restrict__ msg,
                      int C, int g, int t, int Din, char *smem) {
  int bb = g >> 6, r0 = (g & 63) * 4;
  float4 (*rows4)[nN] = (float4 (*)[nN])smem;
  const float4 *L4 = (const float4 *)Lfull;
  for (int e = t; e < 4 * nN; e += Din) {
    int r = e >> 8, j = e & 255;
    rows4[r][j] = L4[((size_t)bb * nN + r0 + r) * nN + j];
  }
  __syncthreads();
  float acc[4][4];
#pragma unroll
  for (int r = 0; r < 4; r++)
#pragma unroll
    for (int e = 0; e < 4; e++) acc[r][e] = 0.f;
  const float *st = state + (size_t)bb * nN * Din + t;
  for (int j = 0; j < nN; j++) {
    float x = st[(size_t)j * Din];
#pragma unroll
    for (int r = 0; r < 4; r++) {
      float4 lv = rows4[r][j];
      acc[r][0] += lv.x * x;
      acc[r][1] += lv.y * x;
      acc[r][2] += lv.z * x;
      acc[r][3] += lv.w * x;
    }
  }
#pragma unroll
  for (int r = 0; r < 4; r++)
#pragma unroll
    for (int e = 0; e < 4; e++)
      msg[((size_t)bb * nN + r0 + r) * C + (6 + e) * Din + t] = acc[r][e];
}

DEV void ddE_body(const float *__restrict__ raw, const float *__restrict__ E,
                  float *__restrict__ F, int g, int t, int Din, char *smem) {
  int k = g % nK, bb = (g / nK) % nB, s = g / (nK * nB);
  float *dr = (float *)smem;
  if (t < nK) {
    int mi = k < t ? k : t, ma = k < t ? t : k;
    dr[t] = raw[((size_t)s * nB + bb) * 400 + mi * nK + ma];
  }
  __syncthreads();
  float acc = 0.f;
  for (int l = 0; l < nK; l++)
    acc += dr[l] * E[((size_t)bb * nK + l) * Din + t];
  F[(((size_t)s * nB + bb) * nK + k) * Din + t] = acc;
}

DEV void longmsg_body(const float *__restrict__ Q, const float *__restrict__ F,
                      float *__restrict__ msg, int C, int g, int t, int Din,
                      char *smem) {
  int i = g % nN, bb = g / nN;
  float *qr = (float *)smem;
  if (t < nK) qr[t] = Q[((size_t)bb * nN + i) * nK + t];
  __syncthreads();
  for (int s = 0; s < 3; s++) {
    float acc = 0.f;
    for (int k = 0; k < nK; k++)
      acc += qr[k] * F[(((size_t)s * nB + bb) * nK + k) * Din + t];
    msg[((size_t)bb * nN + i) * C + (3 + s) * Din + t] = acc;
  }
}

// ---------------- layer-1 merged dispatches (Din = 64) ---------------------
__global__ __launch_bounds__(64) void l1d1_spect_kernel(
    const float *__restrict__ T, float *__restrict__ Tpow2) {
  __shared__ __align__(16) char smem[5120];
  int bb = blockIdx.x & 15, tt = blockIdx.x >> 4;
  spect_body(T, Tpow2, bb, tt, threadIdx.x, smem);
}

__global__ void msgD1_kernel(const float *__restrict__ Q,
                             const float *__restrict__ state,
                             float *__restrict__ E,
                             const float *__restrict__ Lk,
                             float *__restrict__ msg,
                             const float *__restrict__ Lfull, int C) {
  __shared__ __align__(16) char smem[16384];
  int t = threadIdx.x, Din = blockDim.x;
  int gb = blockIdx.x;
  if (gb < nB * nK) {
    qtstate_body(Q, state, E, gb, t, Din, smem);
  } else if (gb < nB * nK + nB * nN / 8) {
    lk_body(Lk, state, Din, msg + 0 * Din, C, gb - nB * nK, t, Din, smem);
  } else {
    edgemsg_body(Lfull, state, msg, C, gb - nB * nK - nB * nN / 8, t, Din, smem);
  }
}

__global__ __launch_bounds__(256) void l1d2_kernel(
    const float *__restrict__ Tpow2, const float *__restrict__ w1p,
    const float *__restrict__ b1p, float *__restrict__ h2,
    const float *__restrict__ Lk, float *__restrict__ msg, int C) {
  __shared__ __align__(16) char smem[26240];  // max(25.6K eig1, 8K lk)
  int t = threadIdx.x;
  int gb = blockIdx.x;
  if (gb < 96) {
    eig1_body(Tpow2, w1p, b1p, h2, gb, t, smem);
  } else {
    int g = gb - 96;
    int bb = g >> 5, r0 = (g & 31) * 8;
    float (*rows)[nN] = (float (*)[nN])smem;
    for (int e = t; e < 8 * nN; e += 256) {
      int r = e >> 8, j = e & 255;
      rows[r][j] = Lk[((size_t)bb * nN + r0 + r) * nN + j];
    }
    __syncthreads();
    if (t < 64) {
      float acc[8] = {0.f, 0.f, 0.f, 0.f, 0.f, 0.f, 0.f, 0.f};
      const float *ip = msg + (size_t)bb * nN * C + 0 * 64 + t;
      for (int j = 0; j < nN; j++) {
        float x = ip[(size_t)j * C];
#pragma unroll
        for (int r = 0; r < 8; r++) acc[r] += rows[r][j] * x;
      }
#pragma unroll
      for (int r = 0; r < 8; r++)
        msg[((size_t)bb * nN + r0 + r) * C + 1 * 64 + t] = acc[r];
    }
  }
}

__global__ __launch_bounds__(256) void l1d3_kernel(
    const float *__restrict__ h2, const float *__restrict__ w2p,
    const float *__restrict__ b2p, float *__restrict__ raw2,
    const float *__restrict__ Lk, float *__restrict__ msg, int C) {
  __shared__ __align__(16) char smem[65600];  // max(65.6K eig2, 8K lk)
  int t = threadIdx.x;
  int gb = blockIdx.x;
  if (gb < 150) {
    eig2_body(h2, w2p, b2p, raw2, gb, t, smem);
  } else {
    int g = gb - 150;
    int bb = g >> 5, r0 = (g & 31) * 8;
    float (*rows)[nN] = (float (*)[nN])smem;
    for (int e = t; e < 8 * nN; e += 256) {
      int r = e >> 8, j = e & 255;
      rows[r][j] = Lk[((size_t)bb * nN + r0 + r) * nN + j];
    }
    __syncthreads();
    if (t < 64) {
      float acc[8] = {0.f, 0.f, 0.f, 0.f, 0.f, 0.f, 0.f, 0.f};
      const float *ip = msg + (size_t)bb * nN * C + 1 * 64 + t;
      for (int j = 0; j < nN; j++) {
        float x = ip[(size_t)j * C];
#pragma unroll
        for (int r = 0; r < 8; r++) acc[r] += rows[r][j] * x;
      }
#pragma unroll
      for (int r = 0; r < 8; r++)
        msg[((size_t)bb * nN + r0 + r) * C + 2 * 64 + t] = acc[r];
    }
  }
}

__global__ void msgD2_kernel(const float *__restrict__ raw,
                             const float *__restrict__ E,
                             float *__restrict__ F,
                             const float *__restrict__ Lk,
                             float *__restrict__ msg, int C, int withLk) {
  __shared__ __align__(16) char smem[8192];
  int t = threadIdx.x, Din = blockDim.x;
  int gb = blockIdx.x;
  if (gb < 3 * nB * nK) {
    ddE_body(raw, E, F, gb, t, Din, smem);
  } else {
    lk_body(Lk, msg + 0 * Din, C, msg + 1 * Din, C, gb - 3 * nB * nK, t, Din,
            smem);
  }
}

__global__ void msgD3_kernel(const float *__restrict__ Q,
                             const float *__restrict__ F,
                             const float *__restrict__ Lk,
                             float *__restrict__ msg, int C) {
  __shared__ __align__(16) char smem[8192];
  int t = threadIdx.x, Din = blockDim.x;
  int gb = blockIdx.x;
  if (gb < nB * nN) {
    longmsg_body(Q, F, msg, C, gb, t, Din, smem);
  } else {
    lk_body(Lk, msg + 1 * Din, C, msg + 2 * Din, C, gb - nB * nN, t, Din, smem);
  }
}

// state_next = relu(msg @ W + b); 16 rows/block, W k-chunk staged in LDS
__global__ __launch_bounds__(256) void filt_kernel(
    const float *__restrict__ msg, const float *__restrict__ W,
    const float *__restrict__ bias, float *__restrict__ out, int C) {
  int g = blockIdx.x;                 // (B*N)/16 = 256 blocks
  int base = g * 16;
  int t = threadIdx.x;
  int o = t & 127, ih = t >> 7;       // ih: 0/1 -> rows 0..7 / 8..15
  __shared__ float mt[16][64];        // 4 KiB
  __shared__ float wt[64][128];       // 32 KiB
  float acc[8];
  float bo = bias[o];
#pragma unroll
  for (int r = 0; r < 8; r++) acc[r] = bo;
  for (int c0 = 0; c0 < C; c0 += 64) {
    __syncthreads();
    for (int e = t; e < 16 * 64; e += 256) {
      int r = e >> 6, c = e & 63;
      mt[r][c] = msg[((size_t)(base + r)) * C + c0 + c];
    }
    for (int e = t; e < 64 * 128; e += 256)
      wt[e >> 7][e & 127] = W[(size_t)(c0 + (e >> 7)) * 128 + (e & 127)];
    __syncthreads();
    for (int c = 0; c < 64; c++) {
      float w = wt[c][o];
#pragma unroll
      for (int r = 0; r < 8; r++) acc[r] += mt[ih * 8 + r][c] * w;
    }
  }
#pragma unroll
  for (int r = 0; r < 8; r++)
    out[((size_t)(base + ih * 8 + r)) * 128 + o] = fmaxf(acc[r], 0.f);
}

// ---------------- stage 6: readout (LDS-staged coalesced reads) ------------
__global__ __launch_bounds__(256) void score_kernel(
    const float *__restrict__ state, const float *__restrict__ wo,
    const float *__restrict__ bo, const float *__restrict__ aw,
    const float *__restrict__ ab, float *__restrict__ out) {
  __shared__ float sl[64 * 129];      // 33 KiB, bank-safe stride
  __shared__ double s4[4];
  int bb = blockIdx.x, t = threadIdx.x;
  float bof = bo[0], abf = ab[0];
  double dsum = 0.0;
  for (int r0 = 0; r0 < nN; r0 += 64) {
    __syncthreads();
    for (int e = t; e < 64 * 128; e += 256) {
      int r = e >> 7, o = e & 127;
      sl[r * 129 + o] = state[((size_t)bb * nN + r0 + r) * 128 + o];
    }
    __syncthreads();
    if (t < 64) {
      const float *sr = sl + t * 129;
      float sy = bof, sa = abf;
      for (int o = 0; o < 128; o++) {
        float v = sr[o];
        sy += v * wo[o];
        sa += v * aw[o];
      }
      float att = 1.f / (1.f + expf(-sa));
      dsum += (double)(att * sy);
    }
  }
  double m = blockSumD(dsum, s4);
  if (t == 0) out[bb] = (float)(m / (double)nN);
}

// ---------------------------------------------------------------------------
extern "C" void kernel_launch(void *const *d_in, const int *in_sizes, int n_in,
                              void *d_out, int out_size, void *d_ws,
                              size_t ws_size, hipStream_t stream) {
  (void)in_sizes; (void)n_in; (void)out_size;
  const int   *node_feat = (const int *)d_in[0];
  const float *Lfull     = (const float *)d_in[1];
  const float *emb_w1    = (const float *)d_in[2];
  const float *emb_b1    = (const float *)d_in[3];
  const float *emb_w2    = (const float *)d_in[4];
  const float *emb_b2    = (const float *)d_in[5];
  const float *eig_w1    = (const float *)d_in[6];
  const float *eig_b1    = (const float *)d_in[7];
  const float *eig_w2    = (const float *)d_in[8];
  const float *eig_b2    = (const float *)d_in[9];
  const float *filt_w0   = (const float *)d_in[10];
  const float *filt_b0   = (const float *)d_in[11];
  const float *filt_w1   = (const float *)d_in[12];
  const float *filt_b1   = (const float *)d_in[13];
  const float *filt_wo   = (const float *)d_in[14];
  const float *filt_bo   = (const float *)d_in[15];
  const float *att_w     = (const float *)d_in[16];
  const float *att_b     = (const float *)d_in[17];

  // workspace layout (floats) — identical to r15
  float *ws   = (float *)d_ws;
  float *G    = ws;                    // B*N*N           = 1048576
  float *msg  = G + 1048576;           // B*N*1280        = 5242880
  float *st0  = msg + 5242880;         // B*N*64
  float *st1  = st0 + 262144;          // B*N*128
  float *st2  = st1 + 524288;          // B*N*128
  float *feat = st2 + 524288;          // B*N*64  (dead after dist2)
  float *table= feat + 262144;         // 64*64
  float *Q    = table + 4096;          // B*N*K
  float *T    = Q + 81920;             // B*K*K
  float *Tpow = T + 6400;              // (layout kept)
  float *DD   = Tpow + 19200;          // (layout kept)
  float *h    = DD + 19200;            // (layout kept)
  float *E    = h + 49152;             // B*K*128
  float *F    = E + 40960;             // 3*B*K*128
  float *Dv   = F + 122880;            // B*N
  double *part   = (double *)(Dv + 4096);   // B*N doubles (8-byte aligned)
  // aliases of dead regions:
  float *GT    = msg;                  // B*N*N (dead after lanczos)
  float *featT = msg + 1048576;        // B*64*256 (dead after dist2)
  float *Tpow2 = feat;                 // 2*3*B*400 = 38400
  float *raw2  = feat + 38400;         // 38400
  float *h2    = feat + 76800;         // 98304 (total 175104 < 262144)
  const size_t needBytes = (size_t)(8220432) * 4;
  if (ws_size < needBytes) return;

  // front-end (sigred folded into arow)
  feat_table_kernel<<<64, 256, 0, stream>>>(emb_w1, emb_b1, emb_w2, emb_b2, table);
  feat_state_tr_kernel<<<nB * 4, 256, 0, stream>>>(node_feat, table, feat,
                                                   featT, st0);
  dist2_kernel<<<nB * 64, 256, 0, stream>>>(feat, featT, G, part);
  arow_kernel<<<nB * nN, 256, 0, stream>>>(Lfull, part, G, Dv);
  lkscale_tr_kernel<<<nB * 16, 256, 0, stream>>>(G, Dv, GT);
  // lanczos
  lanczos_kernel<<<nB, 512, 0, stream>>>(GT, Q, T);

  const int QTB = nB * nK;        // 320
  const int LKB = nB * nN / 8;    // 512
  const int EDB = nB * nN / 4;    // 1024
  const int DDB = 3 * nB * nK;    // 960
  const int LMB = nB * nN;        // 4096

  // ---- layer 1 (Din = 64), eigen pipeline interleaved ----
  {
    int Din = 64, C = 640;
    const float *rawT = raw2;  // tt=0 slice
    l1d1_spect_kernel<<<nB * 2, 64, 0, stream>>>(T, Tpow2);
    msgD1_kernel<<<QTB + LKB + EDB, Din, 0, stream>>>(Q, st0, E, G, msg,
                                                      Lfull, C);
    l1d2_kernel<<<96 + LKB, 256, 0, stream>>>(Tpow2, eig_w1, eig_b1, h2, G,
                                              msg, C);
    l1d3_kernel<<<150 + LKB, 256, 0, stream>>>(h2, eig_w2, eig_b2, raw2, G,
                                               msg, C);
    msgD2_kernel<<<DDB, Din, 0, stream>>>(rawT, E, F, G, msg, C, 0);
    msgD3_kernel<<<LMB, Din, 0, stream>>>(Q, F, G, msg, C);
    filt_kernel<<<nB * nN / 16, 256, 0, stream>>>(msg, filt_w0, filt_b0, st1, C);
  }
  // ---- layer 2 (Din = 128), eigen already done ----
  {
    int Din = 128, C = 1280;
    const float *rawT = raw2 + (size_t)3 * nB * 400;  // tt=1 slice
    msgD1_kernel<<<QTB + LKB + EDB, Din, 0, stream>>>(Q, st1, E, G, msg,
                                                      Lfull, C);
    msgD2_kernel<<<DDB + LKB, Din, 0, stream>>>(rawT, E, F, G, msg, C, 1);
    msgD3_kernel<<<LMB + LKB, Din, 0, stream>>>(Q, F, G, msg, C);
    filt_kernel<<<nB * nN / 16, 256, 0, stream>>>(msg, filt_w1, filt_b1, st2, C);
  }
  score_kernel<<<nB, 256, 0, stream>>>(st2, filt_wo, filt_bo, att_w, att_b,
                                       (float *)d_out);
}

// Round 18
// 602.475 us; speedup vs baseline: 1.1822x; 1.0471x over previous
//
#include <hip/hip_runtime.h>

// ---------------------------------------------------------------------------
// AdaLanczosNet forward, faithful f32 re-implementation of the JAX reference.
// B=16, N=256, NUM_ATOM=64, K=20, HIDDEN=(128,128), SCALES=10.
// Round 18: r17 champion (630us) + hide layer-1's lanczos-independent work
// inside the lanczos dispatch. Blocks 0-15 = lanczos (unchanged body); blocks
// 16..527 = lk1; 528..1551 = edgemsg (stage with 512 threads - order-free
// copies; compute with original 64 lanes -> bit-exact). GT alias moved to
// msg+4194304 so L1 msg writes (first 2.62M floats) can't touch it. qtstate
// folded into l1d2 as third branch (Din=64 semantics, t<64 compute).
// msgD1-L1 dispatch deleted: execution + gap hidden under lanczos' 182us.
// ---------------------------------------------------------------------------

constexpr int nB = 16;
constexpr int nN = 256;
constexpr int nK = 20;
constexpr int QS = nN + 1;  // padded Qb row stride (bank-conflict-free)
constexpr float EPSF = 1.1920928955078125e-07f;  // np.finfo(float32).eps
constexpr float LBF  = 1e-4f;                    // lanczos breakdown tol

#define DEV static __device__ __forceinline__

// ---------------- Threefry-2x32 (20 rounds) --------------------------------
DEV void tf2x32(unsigned k0, unsigned k1, unsigned x0, unsigned x1,
                unsigned &o0, unsigned &o1) {
  unsigned ks2 = k0 ^ k1 ^ 0x1BD11BDAu;
#define RND(r) { x0 += x1; x1 = (x1 << r) | (x1 >> (32 - r)); x1 ^= x0; }
  x0 += k0;  x1 += k1;
  RND(13) RND(15) RND(26) RND(6)
  x0 += k1;  x1 += ks2 + 1u;
  RND(17) RND(29) RND(16) RND(24)
  x0 += ks2; x1 += k0 + 2u;
  RND(13) RND(15) RND(26) RND(6)
  x0 += k0;  x1 += k1 + 3u;
  RND(17) RND(29) RND(16) RND(24)
  x0 += k1;  x1 += ks2 + 4u;
  RND(13) RND(15) RND(26) RND(6)
  x0 += ks2; x1 += k0 + 5u;
#undef RND
  o0 = x0; o1 = x1;
}

// XLA ErfInv (f32, Giles polynomial, w = -log1p(-x^2))
DEV float erfinv_f32(float x) {
  float w = -log1pf(-x * x);
  float p;
  if (w < 5.0f) {
    w -= 2.5f;
    p = 2.81022636e-08f;
    p = fmaf(p, w, 3.43273939e-07f);
    p = fmaf(p, w, -3.5233877e-06f);
    p = fmaf(p, w, -4.39150654e-06f);
    p = fmaf(p, w, 0.00021858087f);
    p = fmaf(p, w, -0.00125372503f);
    p = fmaf(p, w, -0.00417768164f);
    p = fmaf(p, w, 0.246640727f);
    p = fmaf(p, w, 1.50140941f);
  } else {
    w = sqrtf(w) - 3.0f;
    p = -0.000200214257f;
    p = fmaf(p, w, 0.000100950558f);
    p = fmaf(p, w, 0.00134934322f);
    p = fmaf(p, w, -0.00367342844f);
    p = fmaf(p, w, 0.00573950773f);
    p = fmaf(p, w, -0.0076224613f);
    p = fmaf(p, w, 0.00943887047f);
    p = fmaf(p, w, 1.00167406f);
    p = fmaf(p, w, 2.83297682f);
  }
  return p * x;
}

DEV float jax_normal(unsigned k0, unsigned k1, unsigned idx) {
  unsigned o0, o1;
  tf2x32(k0, k1, 0u /*hi*/, idx /*lo*/, o0, o1);
  unsigned bits = o0 ^ o1;
  float u = __uint_as_float((bits >> 9) | 0x3f800000u) - 1.0f;  // [0,1)
  const float lo = -0.99999994f;
  float v = fmaxf(lo, u * 2.0f + lo);
  return 1.41421356237309515f * erfinv_f32(v);
}

// ---------------- reductions ----------------------------------------------
DEV double waveRedD(double v) {
#pragma unroll
  for (int m = 32; m > 0; m >>= 1) v += __shfl_xor(v, m, 64);
  return v;
}
DEV float waveRedF(float v) {
#pragma unroll
  for (int m = 32; m > 0; m >>= 1) v += __shfl_xor(v, m, 64);
  return v;
}
DEV double blockSumD(double v, double *s4) {
  v = waveRedD(v);
  int w = threadIdx.x >> 6;
  __syncthreads();
  if ((threadIdx.x & 63) == 0) s4[w] = v;
  __syncthreads();
  return s4[0] + s4[1] + s4[2] + s4[3];
}
DEV double sum8(const double *r) {
  return ((r[0] + r[1]) + (r[2] + r[3])) + ((r[4] + r[5]) + (r[6] + r[7]));
}

// ---------------- stage 1: embedding table + one-hot state ----------------
__global__ __launch_bounds__(256) void feat_table_kernel(
    const float *__restrict__ w1, const float *__restrict__ b1,
    const float *__restrict__ w2, const float *__restrict__ b2,
    float *__restrict__ table) {
  int a = blockIdx.x, t = threadIdx.x;
  __shared__ float hh[1024];
  __shared__ float part[256];
  for (int k = t; k < 1024; k += 256)
    hh[k] = fmaxf(w1[(size_t)a * 1024 + k] + b1[k], 0.f);
  __syncthreads();
  int d = t & 63, slice = t >> 6;
  float acc = 0.f;
  for (int k = slice * 256; k < slice * 256 + 256; k++)
    acc += hh[k] * w2[(size_t)k * 64 + d];
  part[t] = acc;
  __syncthreads();
  if (t < 64)
    table[(size_t)a * 64 + t] =
        part[t] + part[64 + t] + part[128 + t] + part[192 + t] + b2[t];
}

// fused: feat gather + one-hot state + featT transpose (per 64-node tile)
__global__ __launch_bounds__(256) void feat_state_tr_kernel(
    const int *__restrict__ nf, const float *__restrict__ table,
    float *__restrict__ feat, float *__restrict__ featT,
    float *__restrict__ state0) {
  int g = blockIdx.x;             // nB*4
  int bb = g >> 2, n0 = (g & 3) * 64;
  int t = threadIdx.x;
  int c = t & 63, r4 = t >> 6;
  __shared__ float tl[64][65];
  __shared__ int av[64];
  if (t < 64) av[t] = nf[bb * nN + n0 + t];
  __syncthreads();
  for (int r = r4; r < 64; r += 4) {
    int a = av[r];
    float v = table[(size_t)a * 64 + c];
    tl[r][c] = v;
    feat[((size_t)(bb * nN + n0 + r)) * 64 + c] = v;
    state0[((size_t)(bb * nN + n0 + r)) * 64 + c] = (c == a) ? 1.f : 0.f;
  }
  __syncthreads();
  for (int r = r4; r < 64; r += 4)
    featT[(size_t)bb * 16384 + (size_t)r * nN + n0 + c] = tl[c][r];
}

// ---------------- stage 2: graph laplacian --------------------------------
__global__ __launch_bounds__(256) void dist2_kernel(
    const float *__restrict__ feat, const float *__restrict__ featT,
    float *__restrict__ G, double *__restrict__ part) {
  int g = blockIdx.x;             // nB*64
  int bb = g >> 6, i0 = (g & 63) * 4;
  int t = threadIdx.x;
  __shared__ float fi[4][64];
  __shared__ double s4[4];
  {
    int r = t >> 6, d = t & 63;
    fi[r][d] = feat[((size_t)(bb * nN + i0 + r)) * 64 + d];
  }
  __syncthreads();
  const float *ft = featT + (size_t)bb * 16384 + t;
  float a0 = 0.f, a1 = 0.f, a2 = 0.f, a3 = 0.f;
#pragma unroll 8
  for (int d = 0; d < 64; d++) {
    float x = ft[(size_t)d * nN];
    float d0 = fi[0][d] - x; a0 += d0 * d0;
    float d1 = fi[1][d] - x; a1 += d1 * d1;
    float d2 = fi[2][d] - x; a2 += d2 * d2;
    float d3 = fi[3][d] - x; a3 += d3 * d3;
  }
  size_t base = ((size_t)bb * nN + i0) * nN + t;
  G[base]           = a0;
  G[base + nN]      = a1;
  G[base + 2 * nN]  = a2;
  G[base + 3 * nN]  = a3;
  double tot = blockSumD((double)a0 + (double)a1 + (double)a2 + (double)a3, s4);
  if (t == 0) part[g] = tot;
}

// arow with sigred folded in (wave 0 replays sigred's exact 64-lane reduce)
__global__ __launch_bounds__(256) void arow_kernel(
    const float *__restrict__ Lfull, const double *__restrict__ part,
    float *__restrict__ G, float *__restrict__ Dv) {
  int g = blockIdx.x;
  int i = g % nN, bb = g / nN;
  int t = threadIdx.x;
  __shared__ double s4[4];
  __shared__ float ssig;
  if (t < 64) {
    double v = part[(size_t)bb * 64 + t];
    v = waveRedD(v);
    if (t == 0) ssig = (float)(v / 65536.0);
  }
  __syncthreads();
  float sig = ssig;
  size_t idx2 = ((size_t)bb * nN + i) * nN + t;
  float a = expf(-G[idx2] / sig) * Lfull[idx2 * 4];  // adj mask = L[...,0]
  G[idx2] = a;
  double rs = blockSumD((double)a, s4);
  if (t == 0) {
    float r = (float)rs;
    float pad = (r == 0.f) ? 1.f : 0.f;
    Dv[(size_t)bb * nN + i] = 1.f / sqrtf(r + pad);
  }
}

// scale G in place AND write GT = Lk^T (tiled transpose)
__global__ __launch_bounds__(256) void lkscale_tr_kernel(
    float *__restrict__ G, const float *__restrict__ Dv,
    float *__restrict__ GT) {
  int g = blockIdx.x;                 // nB*16
  int bb = g >> 4, tile = g & 15;
  int ti = (tile >> 2) * 64, tj = (tile & 3) * 64;
  int t = threadIdx.x;
  int lj = t & 63, li0 = t >> 6;
  __shared__ float tl[64][65];
  for (int r = li0; r < 64; r += 4) {
    int i = ti + r;
    size_t idx = ((size_t)bb * nN + i) * nN + tj + lj;
    float v = Dv[(size_t)bb * nN + i] * G[idx] * Dv[(size_t)bb * nN + tj + lj];
    G[idx] = v;
    tl[r][lj] = v;
  }
  __syncthreads();
  for (int r = li0; r < 64; r += 4) {
    int j = tj + r;
    GT[((size_t)bb * nN + j) * nN + ti + lj] = tl[lj][r];
  }
}

// ---------------- stage 3: Lanczos + co-scheduled L1 msg work --------------
// Blocks 0..15: lanczos (body unchanged). Blocks 16..527: lk1. 528..1551:
// edgemsg. Branch bodies stage with all 512 threads (order-free copies) and
// compute with the original 64 lanes (t < 64, Din = 64) -> bit-exact.
__global__ __launch_bounds__(512)
void lanczos_kernel(const float *__restrict__ GT, float *__restrict__ Qout,
                    float *__restrict__ Tout, const float *__restrict__ state0,
                    const float *__restrict__ Lfull, const float *__restrict__ G,
                    float *__restrict__ msg) {
  __shared__ float Qb[nK * QS];          // padded stride 257
  __shared__ float qc[nN], qp[nN], zz[nN];
  __shared__ double zp[2][nN];
  __shared__ float qn2[nK], sAl[nK], sBe[nK], sVa[nK], coef[nK];
  __shared__ double redA[8], redB[8];
  __shared__ __align__(16) char bsmem[16384];
  int gb = blockIdx.x, u = threadIdx.x;

  if (gb >= 16) {
    const int C = 640;
    if (gb < 16 + 512) {
      // ---- lk1: out = Lk @ st0 -> msg part 0 (Din = 64) ----
      int g = gb - 16;
      int bb2 = g >> 5, r0 = (g & 31) * 8;
      float (*rows)[nN] = (float (*)[nN])bsmem;   // 8 KiB
      for (int e = u; e < 8 * nN; e += 512) {
        int r = e >> 8, j = e & 255;
        rows[r][j] = G[((size_t)bb2 * nN + r0 + r) * nN + j];
      }
      __syncthreads();
      if (u < 64) {
        float acc[8] = {0.f, 0.f, 0.f, 0.f, 0.f, 0.f, 0.f, 0.f};
        const float *ip = state0 + (size_t)bb2 * nN * 64 + u;
        for (int j = 0; j < nN; j++) {
          float x = ip[(size_t)j * 64];
#pragma unroll
          for (int r = 0; r < 8; r++) acc[r] += rows[r][j] * x;
        }
#pragma unroll
        for (int r = 0; r < 8; r++)
          msg[((size_t)bb2 * nN + r0 + r) * C + 0 * 64 + u] = acc[r];
      }
    } else {
      // ---- edgemsg: msg parts 6..9 (Din = 64) ----
      int g = gb - 528;
      int bb2 = g >> 6, r0 = (g & 63) * 4;
      float4 (*rows4)[nN] = (float4 (*)[nN])bsmem;  // 16 KiB
      const float4 *L4 = (const float4 *)Lfull;
      for (int e = u; e < 4 * nN; e += 512) {
        int r = e >> 8, j = e & 255;
        rows4[r][j] = L4[((size_t)bb2 * nN + r0 + r) * nN + j];
      }
      __syncthreads();
      if (u < 64) {
        float acc[4][4];
#pragma unroll
        for (int r = 0; r < 4; r++)
#pragma unroll
          for (int e = 0; e < 4; e++) acc[r][e] = 0.f;
        const float *st = state0 + (size_t)bb2 * nN * 64 + u;
        for (int j = 0; j < nN; j++) {
          float x = st[(size_t)j * 64];
#pragma unroll
          for (int r = 0; r < 4; r++) {
            float4 lv = rows4[r][j];
            acc[r][0] += lv.x * x;
            acc[r][1] += lv.y * x;
            acc[r][2] += lv.z * x;
            acc[r][3] += lv.w * x;
          }
        }
#pragma unroll
        for (int r = 0; r < 4; r++)
#pragma unroll
          for (int e = 0; e < 4; e++)
            msg[((size_t)bb2 * nN + r0 + r) * C + (6 + e) * 64 + u] = acc[r][e];
      }
    }
    return;
  }

  int bb = gb, t = u & 255, h = u >> 8;
  int wv = u >> 6, lane = u & 63;
  int gid = u >> 4, gl = u & 15;

  const float *Gcol = GT + (size_t)bb * (nN * nN) + (size_t)(h * 128) * nN + t;

  unsigned k0, k1;
  tf2x32(0u, 42u, 0u, 0u, k0, k1);
  float val = 0.f;
  if (h == 0) val = jax_normal(k0, k1, (unsigned)(bb * nN + t));
  {
    double v = waveRedD((double)val * (double)val);
    __syncthreads();
    if (lane == 0) redA[wv] = v;
    __syncthreads();
    double n2 = sum8(redA);
    if (h == 0) {
      qc[t] = val / sqrtf((float)n2);
      qp[t] = 0.f;
    }
  }
  __syncthreads();

  float beta_prev = 0.f, validf = 1.f;

  for (int i = 0; i < nK; i++) {
    double a0 = 0, a1 = 0, a2 = 0, a3 = 0, a4 = 0, a5 = 0, a6 = 0, a7 = 0;
    {
      const float *qv = qc + h * 128;
#pragma unroll
      for (int jj = 0; jj < 128; jj += 8) {
        a0 += (double)Gcol[(size_t)(jj + 0) * nN] * (double)qv[jj + 0];
        a1 += (double)Gcol[(size_t)(jj + 1) * nN] * (double)qv[jj + 1];
        a2 += (double)Gcol[(size_t)(jj + 2) * nN] * (double)qv[jj + 2];
        a3 += (double)Gcol[(size_t)(jj + 3) * nN] * (double)qv[jj + 3];
        a4 += (double)Gcol[(size_t)(jj + 4) * nN] * (double)qv[jj + 4];
        a5 += (double)Gcol[(size_t)(jj + 5) * nN] * (double)qv[jj + 5];
        a6 += (double)Gcol[(size_t)(jj + 6) * nN] * (double)qv[jj + 6];
        a7 += (double)Gcol[(size_t)(jj + 7) * nN] * (double)qv[jj + 7];
      }
    }
    double part = ((a0 + a1) + (a2 + a3)) + ((a4 + a5) + (a6 + a7));
    zp[h][t] = part;
    double apart = (double)qc[t] * part;
    double qpart = (h == 0) ? (double)qc[t] * (double)qc[t] : 0.0;
    apart = waveRedD(apart);
    qpart = waveRedD(qpart);
    if (lane == 0) { redA[wv] = apart; redB[wv] = qpart; }
    __syncthreads();                                   // B1
    float alpha = (float)sum8(redA);
    if (h == 0) {
      float zi = (float)(zp[0][t] + zp[1][t]);
      zi = zi - alpha * qc[t] - beta_prev * qp[t];
      zz[t] = zi;
    } else {
      Qb[i * QS + t] = qc[t];
      if (t == 0) qn2[i] = (float)sum8(redB);
    }
    __syncthreads();                                   // B2
    if (gid < i) {
      double p = 0.0;
#pragma unroll
      for (int j = 0; j < 16; j++) {
        int n0 = gl + 16 * j;
        p += (double)Qb[gid * QS + n0] * (double)zz[n0];
      }
#pragma unroll
      for (int m = 1; m <= 8; m <<= 1) p += __shfl_xor(p, m, 64);
      if (gl == 0)
        coef[gid] = (float)(p / ((double)qn2[gid] + (double)EPSF));
    }
    __syncthreads();                                   // B3
    if (h == 0) {
      double sub = 0.0;
      for (int k = 0; k < i; k++)
        sub += (double)Qb[k * QS + t] * (double)coef[k];
      zz[t] = (float)((double)zz[t] - sub);
    }
    __syncthreads();                                   // B4
    if (gid < i) {
      double p = 0.0;
#pragma unroll
      for (int j = 0; j < 16; j++) {
        int n0 = gl + 16 * j;
        p += (double)Qb[gid * QS + n0] * (double)zz[n0];
      }
#pragma unroll
      for (int m = 1; m <= 8; m <<= 1) p += __shfl_xor(p, m, 64);
      if (gl == 0)
        coef[gid] = (float)(p / ((double)qn2[gid] + (double)EPSF));
    }
    __syncthreads();                                   // B5
    double bpart = 0.0;
    if (h == 0) {
      double sub = 0.0;
      for (int k = 0; k < i; k++)
        sub += (double)Qb[k * QS + t] * (double)coef[k];
      float znew = (float)((double)zz[t] - sub);
      zz[t] = znew;
      bpart = (double)znew * (double)znew;
    }
    bpart = waveRedD(bpart);
    if (lane == 0) redA[wv] = bpart;
    __syncthreads();                                   // B6
    float beta = sqrtf((float)sum8(redA));
    validf *= (beta >= LBF) ? 1.f : 0.f;
    if (u == 0) {
      sAl[i] = alpha;
      sBe[i] = beta;
      sVa[i] = validf;
    }
    if (h == 0) {
      float qnext = zz[t] * validf / (beta + EPSF);
      qp[t] = qc[t];
      qc[t] = qnext;
    }
    __syncthreads();                                   // B7
    beta_prev = beta;
  }

  float idxf = 0.f;
  for (int k = 0; k < nK; k++) idxf += sVa[k];
  int idx = (int)idxf;
  if (h == 0) {
    float rowok = ((t < idx) || (idx >= nN)) ? 1.f : 0.f;
    for (int k = 0; k < nK; k++)
      Qout[((size_t)bb * nN + t) * nK + k] = Qb[k * QS + t] * sVa[k] * rowok;
  }
  for (int e = u; e < nK * nK; e += 512) {
    int i = e / nK, j = e % nK;
    float v = 0.f;
    if (i == j) v = sAl[i] * sVa[i];
    else if (j == i + 1) v = sBe[i] * sVa[i];
    else if (i == j + 1) v = sBe[j] * sVa[j];
    Tout[(size_t)bb * nK * nK + e] = v;
  }
}

// ---------------- spect_power body (device fn; 64 threads) -----------------
DEV void spect_body(const float *__restrict__ Tin, float *__restrict__ Tpow2,
                    int bb, int tt, int t, char *smem) {
  float *T_  = (float *)smem;                // 400
  float *TT  = T_ + nK * nK;                 // 400
  float *TTn = TT + nK * nK;                 // 400
  float *Tb  = TTn + nK * nK;                // 20
  float *Tbn = Tb + nK;                      // 20
  for (int e = t; e < nK * nK; e += 64) {
    float v = Tin[(size_t)bb * nK * nK + e];
    T_[e] = v;
    TT[e] = v;
  }
  unsigned k0, k1;
  tf2x32(0u, 42u, 0u, (unsigned)(tt + 1), k0, k1);
  if (t < nK) Tb[t] = jax_normal(k0, k1, (unsigned)(bb * nK + t));
  __syncthreads();
  float pv = (t < nK) ? Tb[t] * Tb[t] : 0.f;
  float nb = sqrtf(waveRedF(pv));
  if (t < nK) Tb[t] = Tb[t] / nb;
  __syncthreads();
  for (int ii = 0; ii < 8; ii++) {
    if (ii == 3 || ii == 5 || ii == 7) {
      int s = (ii - 3) / 2;
      int sf = tt * 3 + s;
      for (int e = t; e < nK * nK; e += 64)
        Tpow2[((size_t)sf * nB + bb) * nK * nK + e] = TT[e];
    }
    __syncthreads();
    for (int e = t; e < nK * nK; e += 64) {
      int i = e / nK, j = e % nK;
      float a = 0.f;
      for (int l = 0; l < nK; l++) a += TT[i * nK + l] * T_[l * nK + j];
      TTn[e] = a;
    }
    if (t < nK) {
      float a = 0.f;
      for (int l = 0; l < nK; l++) a += T_[t * nK + l] * Tb[l];
      Tbn[t] = a;
    }
    __syncthreads();
    float pn = (t < nK) ? Tbn[t] * Tb[t] : 0.f;
    float pd = (t < nK) ? Tb[t] * Tb[t] : 0.f;
    float num = waveRedF(pn);
    float den = waveRedF(pd);
    float lmax = num / (den + EPSF);
    float keep = (fabsf(lmax) <= 1.0f) ? 1.f : 0.f;
    __syncthreads();
    for (int e = t; e < nK * nK; e += 64) TT[e] = TTn[e] * keep;
    float p2 = (t < nK) ? Tbn[t] * Tbn[t] : 0.f;
    float nn = sqrtf(waveRedF(p2));
    if (t < nK) Tb[t] = Tbn[t] / (nn + EPSF);
    __syncthreads();
  }
}

// ---------------- eig1 body (device fn; 256 threads) -----------------------
DEV void eig1_body(const float *__restrict__ Tpow2, const float *__restrict__ w1p,
                   const float *__restrict__ b1p, float *__restrict__ h2,
                   int g, int t, char *smem) {
  int oc = g & 15, sf = g >> 4;
  int sw = sf % 3;
  int o = (t & 63) + oc * 64, bbg = t >> 6;
  float *tp = (float *)smem;                 // nB*400 = 25.6 KiB
  for (int e = t; e < nB * 400; e += 256)
    tp[e] = Tpow2[(size_t)sf * nB * 400 + e];
  __syncthreads();
  float bias = b1p[(size_t)sw * 1024 + o];
  float acc0 = bias, acc1 = bias, acc2 = bias, acc3 = bias;
  const float *W = w1p + (size_t)sw * 400 * 1024 + o;
  const float *t0 = tp + (bbg + 0) * 400;
  const float *t1 = tp + (bbg + 4) * 400;
  const float *t2 = tp + (bbg + 8) * 400;
  const float *t3 = tp + (bbg + 12) * 400;
  for (int k = 0; k < 400; k++) {
    float w = W[(size_t)k * 1024];
    acc0 += t0[k] * w;
    acc1 += t1[k] * w;
    acc2 += t2[k] * w;
    acc3 += t3[k] * w;
  }
  h2[((size_t)sf * nB + (bbg + 0))  * 1024 + o] = fmaxf(acc0, 0.f);
  h2[((size_t)sf * nB + (bbg + 4))  * 1024 + o] = fmaxf(acc1, 0.f);
  h2[((size_t)sf * nB + (bbg + 8))  * 1024 + o] = fmaxf(acc2, 0.f);
  h2[((size_t)sf * nB + (bbg + 12)) * 1024 + o] = fmaxf(acc3, 0.f);
}

// ---------------- eig2 body (device fn; 256 threads) -----------------------
DEV void eig2_body(const float *__restrict__ h2, const float *__restrict__ w2p,
                   const float *__restrict__ b2p, float *__restrict__ raw2,
                   int g, int t, char *smem) {
  int kc = g % 25, sf = g / 25;
  int sw = sf % 3;
  int kl = (t & 15) + kc * 16, bb = t >> 4;
  float *hh = (float *)smem;                 // nB*1025 = 65.6 KiB
  for (int e = t; e < nB * 1024; e += 256)
    hh[(e >> 10) * 1025 + (e & 1023)] = h2[(size_t)sf * nB * 1024 + e];
  __syncthreads();
  float acc = b2p[(size_t)sw * 400 + kl];
  const float *W = w2p + (size_t)sw * 1024 * 400 + kl;
  const float *hv = hh + bb * 1025;
  for (int o = 0; o < 1024; o++) acc += hv[o] * W[(size_t)o * 400];
  raw2[((size_t)sf * nB + bb) * 400 + kl] = acc;
}

// ---------------- r12 msg bodies as device fns -----------------------------
DEV void qtstate_body(const float *__restrict__ Q, const float *__restrict__ state,
                      float *__restrict__ E, int g, int t, int Din, char *smem) {
  int k = g % nK, bb = g / nK;
  float *qcol = (float *)smem;
  for (int n = t; n < nN; n += Din)
    qcol[n] = Q[((size_t)bb * nN + n) * nK + k];
  __syncthreads();
  const float *st = state + (size_t)bb * nN * Din;
  float acc = 0.f;
  for (int n = 0; n < nN; n++) acc += qcol[n] * st[(size_t)n * Din + t];
  E[((size_t)bb * nK + k) * Din + t] = acc;
}

DEV void lk_body(const float *__restrict__ Lk, const float *__restrict__ in,
                 int inStride, float *__restrict__ out, int outStride,
                 int g, int t, int Din, char *smem) {
  int bb = g >> 5, r0 = (g & 31) * 8;
  float (*rows)[nN] = (float (*)[nN])smem;
  for (int e = t; e < 8 * nN; e += Din) {
    int r = e >> 8, j = e & 255;
    rows[r][j] = Lk[((size_t)bb * nN + r0 + r) * nN + j];
  }
  __syncthreads();
  float acc[8] = {0.f, 0.f, 0.f, 0.f, 0.f, 0.f, 0.f, 0.f};
  const float *ip = in + (size_t)bb * nN * inStride + t;
  for (int j = 0; j < nN; j++) {
    float x = ip[(size_t)j * inStride];
#pragma unroll
    for (int r = 0; r < 8; r++) acc[r] += rows[r][j] * x;
  }
#pragma unroll
  for (int r = 0; r < 8; r++)
    out[((size_t)bb * nN + r0 + r) * outStride + t] = acc[r];
}

DEV void edgemsg_body(const float *__restrict__ Lfull,
                      const float *__restrict__ state, float *__restrict__ msg,
                      int C, int g, int t, int Din, char *smem) {
  int bb = g >> 6, r0 = (g & 63) * 4;
  float4 (*rows4)[nN] = (float4 (*)[nN])smem;
  const float4 *L4 = (const float4 *)Lfull;
  for (int e = t; e < 4 * nN; e += Din) {
    int r = e >> 8, j = e & 255;
    rows4[r][j] = L4[((size_t)bb * nN + r0 + r) * nN + j];
  }
  __syncthreads();
  float acc[4][4];
#pragma unroll
  for (int r = 0; r < 4; r++)
#pragma unroll
    for (int e = 0; e < 4; e++) acc[r][e] = 0.f;
  const float *st = state + (size_t)bb * nN * Din + t;
  for (int j = 0; j < nN; j++) {
    float x = st[(size_t)j * Din];
#pragma unroll
    for (int r = 0; r < 4; r++) {
      float4 lv = rows4[r][j];
      acc[r][0] += lv.x * x;
      acc[r][1] += lv.y * x;
      acc[r][2] += lv.z * x;
      acc[r][3] += lv.w * x;
    }
  }
#pragma unroll
  for (int r = 0; r < 4; r++)
#pragma unroll
    for (int e = 0; e < 4; e++)
      msg[((size_t)bb * nN + r0 + r) * C + (6 + e) * Din + t] = acc[r][e];
}

DEV void ddE_body(const float *__restrict__ raw, const float *__restrict__ E,
                  float *__restrict__ F, int g, int t, int Din, char *smem) {
  int k = g % nK, bb = (g / nK) % nB, s = g / (nK * nB);
  float *dr = (float *)smem;
  if (t < nK) {
    int mi = k < t ? k : t, ma = k < t ? t : k;
    dr[t] = raw[((size_t)s * nB + bb) * 400 + mi * nK + ma];
  }
  __syncthreads();
  float acc = 0.f;
  for (int l = 0; l < nK; l++)
    acc += dr[l] * E[((size_t)bb * nK + l) * Din + t];
  F[(((size_t)s * nB + bb) * nK + k) * Din + t] = acc;
}

DEV void longmsg_body(const float *__restrict__ Q, const float *__restrict__ F,
                      float *__restrict__ msg, int C, int g, int t, int Din,
                      char *smem) {
  int i = g % nN, bb = g / nN;
  float *qr = (float *)smem;
  if (t < nK) qr[t] = Q[((size_t)bb * nN + i) * nK + t];
  __syncthreads();
  for (int s = 0; s < 3; s++) {
    float acc = 0.f;
    for (int k = 0; k < nK; k++)
      acc += qr[k] * F[(((size_t)s * nB + bb) * nK + k) * Din + t];
    msg[((size_t)bb * nN + i) * C + (3 + s) * Din + t] = acc;
  }
}

// ---------------- merged dispatches ----------------------------------------
__global__ __launch_bounds__(64) void l1d1_spect_kernel(
    const float *__restrict__ T, float *__restrict__ Tpow2) {
  __shared__ __align__(16) char smem[5120];
  int bb = blockIdx.x & 15, tt = blockIdx.x >> 4;
  spect_body(T, Tpow2, bb, tt, threadIdx.x, smem);
}

// L1-D2 (256 thr): eig1(96) || qtstate(320, Din=64 sem.) || lk2(512)
__global__ __launch_bounds__(256) void l1d2_kernel(
    const float *__restrict__ Tpow2, const float *__restrict__ w1p,
    const float *__restrict__ b1p, float *__restrict__ h2,
    const float *__restrict__ Q, const float *__restrict__ state0,
    float *__restrict__ E, const float *__restrict__ Lk,
    float *__restrict__ msg, int C) {
  __shared__ __align__(16) char smem[26240];  // max(25.6K eig1, 8K lk)
  int t = threadIdx.x;
  int gb = blockIdx.x;
  if (gb < 96) {
    eig1_body(Tpow2, w1p, b1p, h2, gb, t, smem);
  } else if (gb < 96 + 320) {
    // qtstate at Din=64 semantics (stage w/ 256, compute w/ 64 lanes)
    int g = gb - 96;
    int k = g % nK, bb = g / nK;
    float *qcol = (float *)smem;
    for (int n = t; n < nN; n += 256)
      qcol[n] = Q[((size_t)bb * nN + n) * nK + k];
    __syncthreads();
    if (t < 64) {
      const float *st = state0 + (size_t)bb * nN * 64;
      float acc = 0.f;
      for (int n = 0; n < nN; n++) acc += qcol[n] * st[(size_t)n * 64 + t];
      E[((size_t)bb * nK + k) * 64 + t] = acc;
    }
  } else {
    int g = gb - 416;
    int bb = g >> 5, r0 = (g & 31) * 8;
    float (*rows)[nN] = (float (*)[nN])smem;
    for (int e = t; e < 8 * nN; e += 256) {
      int r = e >> 8, j = e & 255;
      rows[r][j] = Lk[((size_t)bb * nN + r0 + r) * nN + j];
    }
    __syncthreads();
    if (t < 64) {
      float acc[8] = {0.f, 0.f, 0.f, 0.f, 0.f, 0.f, 0.f, 0.f};
      const float *ip = msg + (size_t)bb * nN * C + 0 * 64 + t;
      for (int j = 0; j < nN; j++) {
        float x = ip[(size_t)j * C];
#pragma unroll
        for (int r = 0; r < 8; r++) acc[r] += rows[r][j] * x;
      }
#pragma unroll
      for (int r = 0; r < 8; r++)
        msg[((size_t)bb * nN + r0 + r) * C + 1 * 64 + t] = acc[r];
    }
  }
}

__global__ __launch_bounds__(256) void l1d3_kernel(
    const float *__restrict__ h2, const float *__restrict__ w2p,
    const float *__restrict__ b2p, float *__restrict__ raw2,
    const float *__restrict__ Lk, float *__restrict__ msg, int C) {
  __shared__ __align__(16) char smem[65600];  // max(65.6K eig2, 8K lk)
  int t = threadIdx.x;
  int gb = blockIdx.x;
  if (gb < 150) {
    eig2_body(h2, w2p, b2p, raw2, gb, t, smem);
  } else {
    int g = gb - 150;
    int bb = g >> 5, r0 = (g & 31) * 8;
    float (*rows)[nN] = (float (*)[nN])smem;
    for (int e = t; e < 8 * nN; e += 256) {
      int r = e >> 8, j = e & 255;
      rows[r][j] = Lk[((size_t)bb * nN + r0 + r) * nN + j];
    }
    __syncthreads();
    if (t < 64) {
      float acc[8] = {0.f, 0.f, 0.f, 0.f, 0.f, 0.f, 0.f, 0.f};
      const float *ip = msg + (size_t)bb * nN * C + 1 * 64 + t;
      for (int j = 0; j < nN; j++) {
        float x = ip[(size_t)j * C];
#pragma unroll
        for (int r = 0; r < 8; r++) acc[r] += rows[r][j] * x;
      }
#pragma unroll
      for (int r = 0; r < 8; r++)
        msg[((size_t)bb * nN + r0 + r) * C + 2 * 64 + t] = acc[r];
    }
  }
}

__global__ void msgD1_kernel(const float *__restrict__ Q,
                             const float *__restrict__ state,
                             float *__restrict__ E,
                             const float *__restrict__ Lk,
                             float *__restrict__ msg,
                             const float *__restrict__ Lfull, int C) {
  __shared__ __align__(16) char smem[16384];
  int t = threadIdx.x, Din = blockDim.x;
  int gb = blockIdx.x;
  if (gb < nB * nK) {
    qtstate_body(Q, state, E, gb, t, Din, smem);
  } else if (gb < nB * nK + nB * nN / 8) {
    lk_body(Lk, state, Din, msg + 0 * Din, C, gb - nB * nK, t, Din, smem);
  } else {
    edgemsg_body(Lfull, state, msg, C, gb - nB * nK - nB * nN / 8, t, Din, smem);
  }
}

__global__ void msgD2_kernel(const float *__restrict__ raw,
                             const float *__restrict__ E,
                             float *__restrict__ F,
                             const float *__restrict__ Lk,
                             float *__restrict__ msg, int C, int withLk) {
  __shared__ __align__(16) char smem[8192];
  int t = threadIdx.x, Din = blockDim.x;
  int gb = blockIdx.x;
  if (gb < 3 * nB * nK) {
    ddE_body(raw, E, F, gb, t, Din, smem);
  } else {
    lk_body(Lk, msg + 0 * Din, C, msg + 1 * Din, C, gb - 3 * nB * nK, t, Din,
            smem);
  }
}

__global__ void msgD3_kernel(const float *__restrict__ Q,
                             const float *__restrict__ F,
                             const float *__restrict__ Lk,
                             float *__restrict__ msg, int C) {
  __shared__ __align__(16) char smem[8192];
  int t = threadIdx.x, Din = blockDim.x;
  int gb = blockIdx.x;
  if (gb < nB * nN) {
    longmsg_body(Q, F, msg, C, gb, t, Din, smem);
  } else {
    lk_body(Lk, msg + 1 * Din, C, msg + 2 * Din, C, gb - nB * nN, t, Din, smem);
  }
}

// state_next = relu(msg @ W + b); 16 rows/block, W k-chunk staged in LDS
__global__ __launch_bounds__(256) void filt_kernel(
    const float *__restrict__ msg, const float *__restrict__ W,
    const float *__restrict__ bias, float *__restrict__ out, int C) {
  int g = blockIdx.x;                 // (B*N)/16 = 256 blocks
  int base = g * 16;
  int t = threadIdx.x;
  int o = t & 127, ih = t >> 7;       // ih: 0/1 -> rows 0..7 / 8..15
  __shared__ float mt[16][64];        // 4 KiB
  __shared__ float wt[64][128];       // 32 KiB
  float acc[8];
  float bo = bias[o];
#pragma unroll
  for (int r = 0; r < 8; r++) acc[r] = bo;
  for (int c0 = 0; c0 < C; c0 += 64) {
    __syncthreads();
    for (int e = t; e < 16 * 64; e += 256) {
      int r = e >> 6, c = e & 63;
      mt[r][c] = msg[((size_t)(base + r)) * C + c0 + c];
    }
    for (int e = t; e < 64 * 128; e += 256)
      wt[e >> 7][e & 127] = W[(size_t)(c0 + (e >> 7)) * 128 + (e & 127)];
    __syncthreads();
    for (int c = 0; c < 64; c++) {
      float w = wt[c][o];
#pragma unroll
      for (int r = 0; r < 8; r++) acc[r] += mt[ih * 8 + r][c] * w;
    }
  }
#pragma unroll
  for (int r = 0; r < 8; r++)
    out[((size_t)(base + ih * 8 + r)) * 128 + o] = fmaxf(acc[r], 0.f);
}

// ---------------- stage 6: readout (LDS-staged coalesced reads) ------------
__global__ __launch_bounds__(256) void score_kernel(
    const float *__restrict__ state, const float *__restrict__ wo,
    const float *__restrict__ bo, const float *__restrict__ aw,
    const float *__restrict__ ab, float *__restrict__ out) {
  __shared__ float sl[64 * 129];      // 33 KiB, bank-safe stride
  __shared__ double s4[4];
  int bb = blockIdx.x, t = threadIdx.x;
  float bof = bo[0], abf = ab[0];
  double dsum = 0.0;
  for (int r0 = 0; r0 < nN; r0 += 64) {
    __syncthreads();
    for (int e = t; e < 64 * 128; e += 256) {
      int r = e >> 7, o = e & 127;
      sl[r * 129 + o] = state[((size_t)bb * nN + r0 + r) * 128 + o];
    }
    __syncthreads();
    if (t < 64) {
      const float *sr = sl + t * 129;
      float sy = bof, sa = abf;
      for (int o = 0; o < 128; o++) {
        float v = sr[o];
        sy += v * wo[o];
        sa += v * aw[o];
      }
      float att = 1.f / (1.f + expf(-sa));
      dsum += (double)(att * sy);
    }
  }
  double m = blockSumD(dsum, s4);
  if (t == 0) out[bb] = (float)(m / (double)nN);
}

// ---------------------------------------------------------------------------
extern "C" void kernel_launch(void *const *d_in, const int *in_sizes, int n_in,
                              void *d_out, int out_size, void *d_ws,
                              size_t ws_size, hipStream_t stream) {
  (void)in_sizes; (void)n_in; (void)out_size;
  const int   *node_feat = (const int *)d_in[0];
  const float *Lfull     = (const float *)d_in[1];
  const float *emb_w1    = (const float *)d_in[2];
  const float *emb_b1    = (const float *)d_in[3];
  const float *emb_w2    = (const float *)d_in[4];
  const float *emb_b2    = (const float *)d_in[5];
  const float *eig_w1    = (const float *)d_in[6];
  const float *eig_b1    = (const float *)d_in[7];
  const float *eig_w2    = (const float *)d_in[8];
  const float *eig_b2    = (const float *)d_in[9];
  const float *filt_w0   = (const float *)d_in[10];
  const float *filt_b0   = (const float *)d_in[11];
  const float *filt_w1   = (const float *)d_in[12];
  const float *filt_b1   = (const float *)d_in[13];
  const float *filt_wo   = (const float *)d_in[14];
  const float *filt_bo   = (const float *)d_in[15];
  const float *att_w     = (const float *)d_in[16];
  const float *att_b     = (const float *)d_in[17];

  // workspace layout (floats)
  float *ws   = (float *)d_ws;
  float *G    = ws;                    // B*N*N           = 1048576
  float *msg  = G + 1048576;           // B*N*1280        = 5242880
  float *st0  = msg + 5242880;         // B*N*64
  float *st1  = st0 + 262144;          // B*N*128
  float *st2  = st1 + 524288;          // B*N*128
  float *feat = st2 + 524288;          // B*N*64  (dead after dist2)
  float *table= feat + 262144;         // 64*64
  float *Q    = table + 4096;          // B*N*K
  float *T    = Q + 81920;             // B*K*K
  float *Tpow = T + 6400;              // (layout kept)
  float *DD   = Tpow + 19200;          // (layout kept)
  float *h    = DD + 19200;            // (layout kept)
  float *E    = h + 49152;             // B*K*128
  float *F    = E + 40960;             // 3*B*K*128
  float *Dv   = F + 122880;            // B*N
  double *part   = (double *)(Dv + 4096);   // B*N doubles (8-byte aligned)
  // aliases of dead regions:
  // GT at the TAIL of the msg region: layer-1 msg writes use only the first
  // 4096*640 = 2621440 floats; GT at +4194304..+5242880 never overlaps them.
  float *GT    = msg + 4194304;        // B*N*N = 1048576 floats
  float *featT = msg + 1048576;        // B*64*256 (dead after dist2)
  float *Tpow2 = feat;                 // 2*3*B*400 = 38400
  float *raw2  = feat + 38400;         // 38400
  float *h2    = feat + 76800;         // 98304 (total 175104 < 262144)
  const size_t needBytes = (size_t)(8220432) * 4;
  if (ws_size < needBytes) return;

  // front-end (sigred folded into arow)
  feat_table_kernel<<<64, 256, 0, stream>>>(emb_w1, emb_b1, emb_w2, emb_b2, table);
  feat_state_tr_kernel<<<nB * 4, 256, 0, stream>>>(node_feat, table, feat,
                                                   featT, st0);
  dist2_kernel<<<nB * 64, 256, 0, stream>>>(feat, featT, G, part);
  arow_kernel<<<nB * nN, 256, 0, stream>>>(Lfull, part, G, Dv);
  lkscale_tr_kernel<<<nB * 16, 256, 0, stream>>>(G, Dv, GT);
  // lanczos + co-scheduled lk1/edgemsg (layer 1)
  lanczos_kernel<<<16 + 512 + 1024, 512, 0, stream>>>(GT, Q, T, st0, Lfull, G,
                                                      msg);

  const int QTB = nB * nK;        // 320
  const int LKB = nB * nN / 8;    // 512
  const int EDB = nB * nN / 4;    // 1024
  const int DDB = 3 * nB * nK;    // 960
  const int LMB = nB * nN;        // 4096

  // ---- layer 1 (Din = 64) ----
  {
    int Din = 64, C = 640;
    const float *rawT = raw2;  // tt=0 slice
    l1d1_spect_kernel<<<nB * 2, 64, 0, stream>>>(T, Tpow2);
    l1d2_kernel<<<96 + QTB + LKB, 256, 0, stream>>>(Tpow2, eig_w1, eig_b1, h2,
                                                    Q, st0, E, G, msg, C);
    l1d3_kernel<<<150 + LKB, 256, 0, stream>>>(h2, eig_w2, eig_b2, raw2, G,
                                               msg, C);
    msgD2_kernel<<<DDB, Din, 0, stream>>>(rawT, E, F, G, msg, C, 0);
    msgD3_kernel<<<LMB, Din, 0, stream>>>(Q, F, G, msg, C);
    filt_kernel<<<nB * nN / 16, 256, 0, stream>>>(msg, filt_w0, filt_b0, st1, C);
  }
  // ---- layer 2 (Din = 128), eigen already done ----
  {
    int Din = 128, C = 1280;
    const float *rawT = raw2 + (size_t)3 * nB * 400;  // tt=1 slice
    msgD1_kernel<<<QTB + LKB + EDB, Din, 0, stream>>>(Q, st1, E, G, msg,
                                                      Lfull, C);
    msgD2_kernel<<<DDB + LKB, Din, 0, stream>>>(rawT, E, F, G, msg, C, 1);
    msgD3_kernel<<<LMB + LKB, Din, 0, stream>>>(Q, F, G, msg, C);
    filt_kernel<<<nB * nN / 16, 256, 0, stream>>>(msg, filt_w1, filt_b1, st2, C);
  }
  score_kernel<<<nB, 256, 0, stream>>>(st2, filt_wo, filt_bo, att_w, att_b,
                                       (float *)d_out);
}